// Round 2
// baseline (1548.378 us; speedup 1.0000x reference)
//
#include <hip/hip_runtime.h>

#define USH unsigned short

// ---------- bf16 helpers (storage = unsigned short) ----------
__device__ __forceinline__ float b2f(USH u) {
    union { unsigned int i; float f; } x; x.i = ((unsigned int)u) << 16; return x.f;
}
__device__ __forceinline__ USH f2b(float f) {
    union { float f; unsigned int i; } x; x.f = f;
    unsigned int r = x.i + (0x7fffu + ((x.i >> 16) & 1u));  // RNE
    return (USH)(r >> 16);
}
__device__ __forceinline__ float ldf(const USH* p)  { return b2f(*p); }
__device__ __forceinline__ float ldf(const float* p){ return *p; }
__device__ __forceinline__ void stf(USH* p, float v)  { *p = f2b(v); }
__device__ __forceinline__ void stf(float* p, float v){ *p = v; }

// load 8 consecutive elements as f32
__device__ __forceinline__ void ldv8(const USH* p, float* o) {
    int4 t = *(const int4*)p; const USH* u = (const USH*)&t;
#pragma unroll
    for (int e = 0; e < 8; e++) o[e] = b2f(u[e]);
}
__device__ __forceinline__ void ldv8(const float* p, float* o) {
    float4 a = *(const float4*)p, b = *(const float4*)(p + 4);
    o[0]=a.x; o[1]=a.y; o[2]=a.z; o[3]=a.w; o[4]=b.x; o[5]=b.y; o[6]=b.z; o[7]=b.w;
}

typedef __attribute__((ext_vector_type(8))) __bf16 bf16x8;
typedef __attribute__((ext_vector_type(4))) float  floatx4;

// =====================================================================
// dtype detector: ln1_g is all-ones. bf16 1.0 -> word0 = 0x3F80;
// f32 1.0 little-endian -> word0 = 0x0000. flag: 0 = bf16, 1 = f32.
// =====================================================================
__global__ void detect_k(const USH* __restrict__ ln1g, int* __restrict__ flag) {
    if (threadIdx.x == 0) *flag = (ln1g[0] == 0x3F80u) ? 0 : 1;
}

// =====================================================================
// LayerNorm over rows of length 1024. block=256, one block per row.
// TX = input dtype, TP = gamma/beta dtype. Output always bf16 (ws).
// =====================================================================
template <typename TX, typename TP>
__global__ __launch_bounds__(256) void ln_rows(const int* __restrict__ flag, int want,
                                               const TX* __restrict__ x,
                                               const TP* __restrict__ g,
                                               const TP* __restrict__ bb,
                                               USH* __restrict__ y) {
    if (*flag != want) return;
    int row = blockIdx.x, tid = threadIdx.x;
    const TX* xr = x + (size_t)row * 1024 + tid * 4;
    float v[4];
#pragma unroll
    for (int i = 0; i < 4; i++) v[i] = ldf(xr + i);
    float s  = v[0] + v[1] + v[2] + v[3];
    float ss = v[0]*v[0] + v[1]*v[1] + v[2]*v[2] + v[3]*v[3];
#pragma unroll
    for (int o = 32; o; o >>= 1) { s += __shfl_down(s, o); ss += __shfl_down(ss, o); }
    __shared__ float red[10];
    int w = tid >> 6;
    if ((tid & 63) == 0) { red[w] = s; red[4 + w] = ss; }
    __syncthreads();
    if (tid == 0) {
        float S = red[0] + red[1] + red[2] + red[3];
        float SS = red[4] + red[5] + red[6] + red[7];
        float mean = S * (1.f / 1024.f);
        float var  = SS * (1.f / 1024.f) - mean * mean;
        red[8] = mean; red[9] = rsqrtf(var + 1e-5f);
    }
    __syncthreads();
    float mean = red[8], rstd = red[9];
    USH* yr = y + (size_t)row * 1024 + tid * 4;
#pragma unroll
    for (int i = 0; i < 4; i++) {
        int c = tid * 4 + i;
        yr[i] = f2b((v[i] - mean) * rstd * ldf(g + c) + ldf(bb + c));
    }
}

// =====================================================================
// zh = z @ wca + bca   (4096 rows, K=64, N=256) -> f32 out (ws)
// =====================================================================
template <typename T>
__global__ __launch_bounds__(256) void zh_kernel(const int* __restrict__ flag, int want,
                                                 const T* __restrict__ z,
                                                 const T* __restrict__ wca,
                                                 const T* __restrict__ bca,
                                                 float* __restrict__ zh) {
    if (*flag != want) return;
    int row = blockIdx.x, n = threadIdx.x;
    __shared__ float zrow[64];
    if (n < 64) zrow[n] = ldf(z + (size_t)row * 64 + n);
    __syncthreads();
    float s = ldf(bca + n);
#pragma unroll 8
    for (int k = 0; k < 64; k++) s = fmaf(zrow[k], ldf(wca + (size_t)k * 256 + n), s);
    zh[(size_t)row * 256 + n] = s;
}

// =====================================================================
// z_next = hn @ wcn + bcn  (4096 rows, K=1024, N=64) -> f32 out (ws)
// hn is always bf16 (ws).
// =====================================================================
template <typename T>
__global__ __launch_bounds__(256) void znext_kernel(const int* __restrict__ flag, int want,
                                                    const USH* __restrict__ hn,
                                                    const T* __restrict__ wcn,
                                                    const T* __restrict__ bcn,
                                                    float* __restrict__ zn) {
    if (*flag != want) return;
    int row = blockIdx.x, t = threadIdx.x;
    int n = t & 63, ks = t >> 6;
    const USH* a = hn + (size_t)row * 1024 + ks * 256;
    const T* w = wcn + (size_t)ks * 256 * 64 + n;
    float s = 0.f;
#pragma unroll 4
    for (int k = 0; k < 256; k++) s = fmaf(b2f(a[k]), ldf(w + (size_t)k * 64), s);
    __shared__ float part[4][64];
    part[ks][n] = s;
    __syncthreads();
    if (t < 64)
        zn[(size_t)row * 64 + t] = part[0][t] + part[1][t] + part[2][t] + part[3][t] + ldf(bcn + t);
}

// =====================================================================
// MFMA GEMM: C[M,N] = A[M,K](bf16 ws) @ W[K,N](TW) + bias, epilogue
// 128x128 tile, 4 waves (2x2 of 64x64), BK=32, mfma_f32_16x16x32_bf16
// EPI: 0 = plain | 1 = +res | 2 = gelu | 3 = +res   (out dtype = TOUT)
// =====================================================================
template <int EPI, typename TW, typename TRES, typename TOUT>
__global__ __launch_bounds__(256) void gemm_kernel(const int* __restrict__ flag, int want,
                                                   const USH* __restrict__ A,
                                                   const TW* __restrict__ W,
                                                   const TW* __restrict__ bias,
                                                   const TRES* __restrict__ res,
                                                   TOUT* __restrict__ out,
                                                   int M, int N, int K) {
    if (*flag != want) return;
    __shared__ __align__(16) USH lA[128][40];  // [m][k], pad 32->40
    __shared__ __align__(16) USH lB[128][40];  // [n][k] (W tile transposed)
    int tid = threadIdx.x;
    int lane = tid & 63, wave = tid >> 6;
    int wr = wave >> 1, wc = wave & 1;
    int quad = lane >> 4, l15 = lane & 15;
    int m0 = blockIdx.y * 128, n0 = blockIdx.x * 128;

    int a_row = tid >> 2, a_k = (tid & 3) * 8;   // + r*64 rows
    int w_k = tid >> 4, w_n = (tid & 15) * 8;    // + r*16 k

    floatx4 acc[4][4] = {};

    for (int k0 = 0; k0 < K; k0 += 32) {
#pragma unroll
        for (int r = 0; r < 2; r++) {
            int row = a_row + r * 64;
            *(int4*)&lA[row][a_k] = *(const int4*)(A + (size_t)(m0 + row) * K + k0 + a_k);
        }
#pragma unroll
        for (int r = 0; r < 2; r++) {
            int kk = w_k + r * 16;
            float wv8[8];
            ldv8(W + (size_t)(k0 + kk) * N + n0 + w_n, wv8);
#pragma unroll
            for (int e = 0; e < 8; e++) lB[w_n + e][kk] = f2b(wv8[e]);
        }
        __syncthreads();
        bf16x8 bfr[4];
#pragma unroll
        for (int ni = 0; ni < 4; ni++)
            bfr[ni] = *(const bf16x8*)&lB[wc * 64 + ni * 16 + l15][quad * 8];
#pragma unroll
        for (int mi = 0; mi < 4; mi++) {
            bf16x8 afr = *(const bf16x8*)&lA[wr * 64 + mi * 16 + l15][quad * 8];
#pragma unroll
            for (int ni = 0; ni < 4; ni++)
                acc[mi][ni] = __builtin_amdgcn_mfma_f32_16x16x32_bf16(afr, bfr[ni], acc[mi][ni], 0, 0, 0);
        }
        __syncthreads();
    }

    float bias_v[4];
#pragma unroll
    for (int ni = 0; ni < 4; ni++) bias_v[ni] = ldf(bias + n0 + wc * 64 + ni * 16 + l15);

#pragma unroll
    for (int mi = 0; mi < 4; mi++) {
#pragma unroll
        for (int r = 0; r < 4; r++) {
            int row = m0 + wr * 64 + mi * 16 + quad * 4 + r;
            size_t base = (size_t)row * N;
#pragma unroll
            for (int ni = 0; ni < 4; ni++) {
                int col = n0 + wc * 64 + ni * 16 + l15;
                float v = acc[mi][ni][r] + bias_v[ni];
                if (EPI == 2) v = 0.5f * v * (1.f + erff(v * 0.70710678118f));
                if (EPI == 1 || EPI == 3) v += ldf(res + base + col);
                stf(out + base + col, v);
            }
        }
    }
}

// =====================================================================
// Flash-style distance attention.
// score(q,k) = -softplus(gamma_h) * max(|zq|^2+|zk|^2-2 zq.zk, 0)
// block = 128 threads (one query each), grid = (B*H, S/128)
// zh f32 (ws), value bf16 (ws); only gamma comes from d_in.
// =====================================================================
template <typename TG>
__global__ __launch_bounds__(128) void attn_kernel(const int* __restrict__ flag, int want,
                                                   const float* __restrict__ zh,
                                                   const USH* __restrict__ value,
                                                   const TG* __restrict__ gamma,
                                                   USH* __restrict__ attn_out) {
    if (*flag != want) return;
    int bh = blockIdx.x;
    int b = bh >> 4, h = bh & 15;
    int tid = threadIdx.x;
    int q = blockIdx.y * 128 + tid;

    __shared__ __align__(16) float Kc[64][16];
    __shared__ float Ks[64];
    __shared__ __align__(16) float Vv[64][64];

    const float* zq = zh + ((size_t)(b * 2048 + q)) * 256 + h * 16;
    float qc[16], qsq = 0.f;
#pragma unroll
    for (int c = 0; c < 16; c++) { qc[c] = zq[c]; qsq += qc[c] * qc[c]; }
    float gx = ldf(gamma + h);
    float gv = log1pf(__expf(gx));  // softplus

    float m = -1e30f, l = 0.f, acc[64];
#pragma unroll
    for (int j = 0; j < 64; j++) acc[j] = 0.f;

    for (int kt = 0; kt < 2048; kt += 64) {
        __syncthreads();
        for (int i = tid; i < 256; i += 128) {   // Kc: 64x16 f32 as float4s
            int kk = i >> 2, c0 = (i & 3) * 4;
            *(float4*)&Kc[kk][c0] =
                *(const float4*)(zh + ((size_t)(b * 2048 + kt + kk)) * 256 + h * 16 + c0);
        }
        for (int i = tid; i < 512; i += 128) {   // Vv: 64x64 bf16 -> f32
            int kk = i >> 3, j0 = (i & 7) * 8;
            int4 t = *(const int4*)(value + ((size_t)(b * 2048 + kt + kk)) * 1024 + h * 64 + j0);
            const USH* u = (const USH*)&t;
#pragma unroll
            for (int e = 0; e < 8; e++) Vv[kk][j0 + e] = b2f(u[e]);
        }
        __syncthreads();
        if (tid < 64) {
            float s = 0.f;
#pragma unroll
            for (int c = 0; c < 16; c++) s += Kc[tid][c] * Kc[tid][c];
            Ks[tid] = s;
        }
        __syncthreads();

        for (int kk = 0; kk < 64; kk++) {
            float dot = 0.f;
#pragma unroll
            for (int c = 0; c < 16; c++) dot = fmaf(qc[c], Kc[kk][c], dot);
            float d = fmaxf(qsq + Ks[kk] - 2.f * dot, 0.f);
            float sc = -gv * d;
            if (sc > m) {
                float alpha = __expf(m - sc);
                m = sc; l *= alpha;
#pragma unroll
                for (int j = 0; j < 64; j++) acc[j] *= alpha;
            }
            float p = __expf(sc - m);
            l += p;
#pragma unroll
            for (int j = 0; j < 64; j++) acc[j] = fmaf(p, Vv[kk][j], acc[j]);
        }
    }
    float inv = 1.f / l;
    USH* o = attn_out + ((size_t)(b * 2048 + q)) * 1024 + h * 64;
#pragma unroll
    for (int j = 0; j < 64; j++) o[j] = f2b(acc[j] * inv);
}

// =====================================================================
// z_out = LN(z + z_next) over rows of 64. block = 64 (one wave) per row.
// =====================================================================
template <typename T>
__global__ __launch_bounds__(64) void lnc_kernel(const int* __restrict__ flag, int want,
                                                 const T* __restrict__ z,
                                                 const float* __restrict__ zn,
                                                 const T* __restrict__ g,
                                                 const T* __restrict__ bb,
                                                 T* __restrict__ out) {
    if (*flag != want) return;
    int row = blockIdx.x, t = threadIdx.x;
    float v = ldf(z + (size_t)row * 64 + t) + zn[(size_t)row * 64 + t];
    float s = v, ss = v * v;
#pragma unroll
    for (int o = 32; o; o >>= 1) { s += __shfl_xor(s, o); ss += __shfl_xor(ss, o); }
    float mean = s * (1.f / 64.f);
    float rstd = rsqrtf(ss * (1.f / 64.f) - mean * mean + 1e-5f);
    stf(out + (size_t)row * 64 + t, (v - mean) * rstd * ldf(g + t) + ldf(bb + t));
}

// =====================================================================
extern "C" void kernel_launch(void* const* d_in, const int* in_sizes, int n_in,
                              void* d_out, int out_size, void* d_ws, size_t ws_size,
                              hipStream_t stream) {
    // workspace layout (49 MB + 4 B):
    //   [0,8M)    value (bf16)       -- dead after attn
    //   [8M,16M)  attn_o (bf16)      -- dead after wo-gemm
    //   [16M,20M) zh (f32)           -- dead after attn
    //   [20M,28M) hn (bf16)          -- dead after znext
    //   [0,32M)   mid (bf16)         -- overlays the four above (written later)
    //   [32M,40M) hn2 (bf16)
    //   [40M,48M) h1 (bf16)
    //   [48M,49M) znext (f32)
    //   [49M]     dtype flag (int)
    char* p = (char*)d_ws;
    USH*   value  = (USH*)(p);
    USH*   attn_o = (USH*)(p + ((size_t)8  << 20));
    float* zh     = (float*)(p + ((size_t)16 << 20));
    USH*   hn     = (USH*)(p + ((size_t)20 << 20));
    USH*   mid    = (USH*)(p);
    USH*   hn2    = (USH*)(p + ((size_t)32 << 20));
    USH*   h1     = (USH*)(p + ((size_t)40 << 20));
    float* znext  = (float*)(p + ((size_t)48 << 20));
    int*   flag   = (int*)(p + ((size_t)49 << 20));

    // bf16-typed views of inputs
    const USH *h_b = (const USH*)d_in[0], *z_b = (const USH*)d_in[1];
    const USH *wv_b = (const USH*)d_in[2], *bv_b = (const USH*)d_in[3];
    const USH *wca_b = (const USH*)d_in[4], *bca_b = (const USH*)d_in[5];
    const USH *wcn_b = (const USH*)d_in[6], *bcn_b = (const USH*)d_in[7];
    const USH *wo_b = (const USH*)d_in[8], *bo_b = (const USH*)d_in[9];
    const USH *gam_b = (const USH*)d_in[10];
    const USH *w1_b = (const USH*)d_in[11], *b1_b = (const USH*)d_in[12];
    const USH *w2_b = (const USH*)d_in[13], *b2_b = (const USH*)d_in[14];
    const USH *ln1g_b = (const USH*)d_in[15], *ln1b_b = (const USH*)d_in[16];
    const USH *ln2g_b = (const USH*)d_in[17], *ln2b_b = (const USH*)d_in[18];
    const USH *lncg_b = (const USH*)d_in[19], *lncb_b = (const USH*)d_in[20];
    // f32-typed views of inputs
    const float *h_f = (const float*)d_in[0], *z_f = (const float*)d_in[1];
    const float *wv_f = (const float*)d_in[2], *bv_f = (const float*)d_in[3];
    const float *wca_f = (const float*)d_in[4], *bca_f = (const float*)d_in[5];
    const float *wcn_f = (const float*)d_in[6], *bcn_f = (const float*)d_in[7];
    const float *wo_f = (const float*)d_in[8], *bo_f = (const float*)d_in[9];
    const float *gam_f = (const float*)d_in[10];
    const float *w1_f = (const float*)d_in[11], *b1_f = (const float*)d_in[12];
    const float *w2_f = (const float*)d_in[13], *b2_f = (const float*)d_in[14];
    const float *ln1g_f = (const float*)d_in[15], *ln1b_f = (const float*)d_in[16];
    const float *ln2g_f = (const float*)d_in[17], *ln2b_f = (const float*)d_in[18];
    const float *lncg_f = (const float*)d_in[19], *lncb_f = (const float*)d_in[20];

    USH*   outh_b = (USH*)d_out;
    USH*   outz_b = outh_b + (size_t)4096 * 1024;
    float* outh_f = (float*)d_out;
    float* outz_f = outh_f + (size_t)4096 * 1024;

    detect_k<<<1, 1, 0, stream>>>(ln1g_b, flag);

    // 1. hn = LN1(h)
    ln_rows<USH, USH><<<4096, 256, 0, stream>>>(flag, 0, h_b, ln1g_b, ln1b_b, hn);
    ln_rows<float, float><<<4096, 256, 0, stream>>>(flag, 1, h_f, ln1g_f, ln1b_f, hn);
    // 2. zh = z @ wca + bca
    zh_kernel<USH><<<4096, 256, 0, stream>>>(flag, 0, z_b, wca_b, bca_b, zh);
    zh_kernel<float><<<4096, 256, 0, stream>>>(flag, 1, z_f, wca_f, bca_f, zh);
    // 3. value = hn @ wv + bv
    gemm_kernel<0, USH, USH, USH><<<dim3(8, 32), 256, 0, stream>>>(flag, 0, hn, wv_b, bv_b, (const USH*)nullptr, value, 4096, 1024, 1024);
    gemm_kernel<0, float, USH, USH><<<dim3(8, 32), 256, 0, stream>>>(flag, 1, hn, wv_f, bv_f, (const USH*)nullptr, value, 4096, 1024, 1024);
    // 4. z_next = hn @ wcn + bcn
    znext_kernel<USH><<<4096, 256, 0, stream>>>(flag, 0, hn, wcn_b, bcn_b, znext);
    znext_kernel<float><<<4096, 256, 0, stream>>>(flag, 1, hn, wcn_f, bcn_f, znext);
    // 5. attention
    attn_kernel<USH><<<dim3(32, 16), 128, 0, stream>>>(flag, 0, zh, value, gam_b, attn_o);
    attn_kernel<float><<<dim3(32, 16), 128, 0, stream>>>(flag, 1, zh, value, gam_f, attn_o);
    // 6. h1 = h + attn_o @ wo + bo   (bf16)
    gemm_kernel<1, USH, USH, USH><<<dim3(8, 32), 256, 0, stream>>>(flag, 0, attn_o, wo_b, bo_b, h_b, h1, 4096, 1024, 1024);
    gemm_kernel<1, float, float, USH><<<dim3(8, 32), 256, 0, stream>>>(flag, 1, attn_o, wo_f, bo_f, h_f, h1, 4096, 1024, 1024);
    // 7. hn2 = LN2(h1)
    ln_rows<USH, USH><<<4096, 256, 0, stream>>>(flag, 0, h1, ln2g_b, ln2b_b, hn2);
    ln_rows<USH, float><<<4096, 256, 0, stream>>>(flag, 1, h1, ln2g_f, ln2b_f, hn2);
    // 8. mid = gelu(hn2 @ w1 + b1)   (overlays value/attn_o/zh/hn)
    gemm_kernel<2, USH, USH, USH><<<dim3(32, 32), 256, 0, stream>>>(flag, 0, hn2, w1_b, b1_b, (const USH*)nullptr, mid, 4096, 4096, 1024);
    gemm_kernel<2, float, USH, USH><<<dim3(32, 32), 256, 0, stream>>>(flag, 1, hn2, w1_f, b1_f, (const USH*)nullptr, mid, 4096, 4096, 1024);
    // 9. out_h = h1 + mid @ w2 + b2
    gemm_kernel<3, USH, USH, USH><<<dim3(8, 32), 256, 0, stream>>>(flag, 0, mid, w2_b, b2_b, h1, outh_b, 4096, 1024, 4096);
    gemm_kernel<3, float, USH, float><<<dim3(8, 32), 256, 0, stream>>>(flag, 1, mid, w2_f, b2_f, h1, outh_f, 4096, 1024, 4096);
    // 10. out_z = LN(z + znext)
    lnc_kernel<USH><<<4096, 64, 0, stream>>>(flag, 0, z_b, znext, lncg_b, lncb_b, outz_b);
    lnc_kernel<float><<<4096, 64, 0, stream>>>(flag, 1, z_f, znext, lncg_f, lncb_f, outz_f);
}

// Round 4
// 862.132 us; speedup vs baseline: 1.7960x; 1.7960x over previous
//
#include <hip/hip_runtime.h>

#define USH unsigned short

// ---------- bf16 helpers (storage = unsigned short) ----------
__device__ __forceinline__ float b2f(USH u) {
    union { unsigned int i; float f; } x; x.i = ((unsigned int)u) << 16; return x.f;
}
__device__ __forceinline__ USH f2b(float f) {
    union { float f; unsigned int i; } x; x.f = f;
    unsigned int r = x.i + (0x7fffu + ((x.i >> 16) & 1u));  // RNE
    return (USH)(r >> 16);
}
__device__ __forceinline__ float ldf(const USH* p)  { return b2f(*p); }
__device__ __forceinline__ float ldf(const float* p){ return *p; }
__device__ __forceinline__ void stf(USH* p, float v)  { *p = f2b(v); }
__device__ __forceinline__ void stf(float* p, float v){ *p = v; }

typedef __attribute__((ext_vector_type(8))) __bf16 bf16x8;
typedef __attribute__((ext_vector_type(4))) float  floatx4;

// =====================================================================
// LayerNorm rows of 1024. block=256, one block/row. TX = f32 or bf16(ws).
// Params f32 (d_in). Output bf16 (ws).
// =====================================================================
template <typename TX>
__global__ __launch_bounds__(256) void ln_rows(const TX* __restrict__ x,
                                               const float* __restrict__ g,
                                               const float* __restrict__ bb,
                                               USH* __restrict__ y) {
    int row = blockIdx.x, tid = threadIdx.x;
    const TX* xr = x + (size_t)row * 1024 + tid * 4;
    float v[4];
#pragma unroll
    for (int i = 0; i < 4; i++) v[i] = ldf(xr + i);
    float s  = v[0] + v[1] + v[2] + v[3];
    float ss = v[0]*v[0] + v[1]*v[1] + v[2]*v[2] + v[3]*v[3];
#pragma unroll
    for (int o = 32; o; o >>= 1) { s += __shfl_down(s, o); ss += __shfl_down(ss, o); }
    __shared__ float red[10];
    int w = tid >> 6;
    if ((tid & 63) == 0) { red[w] = s; red[4 + w] = ss; }
    __syncthreads();
    if (tid == 0) {
        float S = red[0] + red[1] + red[2] + red[3];
        float SS = red[4] + red[5] + red[6] + red[7];
        float mean = S * (1.f / 1024.f);
        float var  = SS * (1.f / 1024.f) - mean * mean;
        red[8] = mean; red[9] = rsqrtf(var + 1e-5f);
    }
    __syncthreads();
    float mean = red[8], rstd = red[9];
    USH* yr = y + (size_t)row * 1024 + tid * 4;
#pragma unroll
    for (int i = 0; i < 4; i++) {
        int c = tid * 4 + i;
        yr[i] = f2b((v[i] - mean) * rstd * g[c] + bb[c]);
    }
}

// =====================================================================
// zh = z @ wca + bca   (4096 rows, K=64, N=256) f32 in -> f32 out (ws)
// =====================================================================
__global__ __launch_bounds__(256) void zh_kernel(const float* __restrict__ z,
                                                 const float* __restrict__ wca,
                                                 const float* __restrict__ bca,
                                                 float* __restrict__ zh) {
    int row = blockIdx.x, n = threadIdx.x;
    __shared__ float zrow[64];
    if (n < 64) zrow[n] = z[(size_t)row * 64 + n];
    __syncthreads();
    float s = bca[n];
#pragma unroll 8
    for (int k = 0; k < 64; k++) s = fmaf(zrow[k], wca[(size_t)k * 256 + n], s);
    zh[(size_t)row * 256 + n] = s;
}

// =====================================================================
// z_next = hn(bf16 ws) @ wcn(f32) + bcn  (4096 rows, K=1024, N=64) -> f32
// =====================================================================
__global__ __launch_bounds__(256) void znext_kernel(const USH* __restrict__ hn,
                                                    const float* __restrict__ wcn,
                                                    const float* __restrict__ bcn,
                                                    float* __restrict__ zn) {
    int row = blockIdx.x, t = threadIdx.x;
    int n = t & 63, ks = t >> 6;
    const USH* a = hn + (size_t)row * 1024 + ks * 256;
    const float* w = wcn + (size_t)ks * 256 * 64 + n;
    float s = 0.f;
#pragma unroll 4
    for (int k = 0; k < 256; k++) s = fmaf(b2f(a[k]), w[(size_t)k * 64], s);
    __shared__ float part[4][64];
    part[ks][n] = s;
    __syncthreads();
    if (t < 64)
        zn[(size_t)row * 64 + t] = part[0][t] + part[1][t] + part[2][t] + part[3][t] + bcn[t];
}

// =====================================================================
// MFMA GEMM: C[M,N] = A[M,K](bf16 ws) @ W[K,N](f32 d_in) + bias(f32)
// 128x128 tile, 4 waves (2x2 of 64x64), BK=32, mfma_f32_16x16x32_bf16
// EPI: 0 = plain | 1 = +res | 2 = gelu | 3 = +res
// =====================================================================
template <int EPI, typename TRES, typename TOUT>
__global__ __launch_bounds__(256) void gemm_kernel(const USH* __restrict__ A,
                                                   const float* __restrict__ W,
                                                   const float* __restrict__ bias,
                                                   const TRES* __restrict__ res,
                                                   TOUT* __restrict__ out,
                                                   int M, int N, int K) {
    __shared__ __align__(16) USH lA[128][40];  // [m][k], pad 32->40
    __shared__ __align__(16) USH lB[128][40];  // [n][k] (W tile transposed)
    int tid = threadIdx.x;
    int lane = tid & 63, wave = tid >> 6;
    int wr = wave >> 1, wc = wave & 1;
    int quad = lane >> 4, l15 = lane & 15;
    int m0 = blockIdx.y * 128, n0 = blockIdx.x * 128;

    int a_row = tid >> 2, a_k = (tid & 3) * 8;   // + r*64 rows
    int w_k = tid >> 4, w_n = (tid & 15) * 8;    // + r*16 k

    floatx4 acc[4][4] = {};

    for (int k0 = 0; k0 < K; k0 += 32) {
#pragma unroll
        for (int r = 0; r < 2; r++) {
            int row = a_row + r * 64;
            *(int4*)&lA[row][a_k] = *(const int4*)(A + (size_t)(m0 + row) * K + k0 + a_k);
        }
#pragma unroll
        for (int r = 0; r < 2; r++) {
            int kk = w_k + r * 16;
            const float* src = W + (size_t)(k0 + kk) * N + n0 + w_n;
            float4 fa = *(const float4*)src, fb = *(const float4*)(src + 4);
            lB[w_n + 0][kk] = f2b(fa.x); lB[w_n + 1][kk] = f2b(fa.y);
            lB[w_n + 2][kk] = f2b(fa.z); lB[w_n + 3][kk] = f2b(fa.w);
            lB[w_n + 4][kk] = f2b(fb.x); lB[w_n + 5][kk] = f2b(fb.y);
            lB[w_n + 6][kk] = f2b(fb.z); lB[w_n + 7][kk] = f2b(fb.w);
        }
        __syncthreads();
        bf16x8 bfr[4];
#pragma unroll
        for (int ni = 0; ni < 4; ni++)
            bfr[ni] = *(const bf16x8*)&lB[wc * 64 + ni * 16 + l15][quad * 8];
#pragma unroll
        for (int mi = 0; mi < 4; mi++) {
            bf16x8 afr = *(const bf16x8*)&lA[wr * 64 + mi * 16 + l15][quad * 8];
#pragma unroll
            for (int ni = 0; ni < 4; ni++)
                acc[mi][ni] = __builtin_amdgcn_mfma_f32_16x16x32_bf16(afr, bfr[ni], acc[mi][ni], 0, 0, 0);
        }
        __syncthreads();
    }

    float bias_v[4];
#pragma unroll
    for (int ni = 0; ni < 4; ni++) bias_v[ni] = bias[n0 + wc * 64 + ni * 16 + l15];

#pragma unroll
    for (int mi = 0; mi < 4; mi++) {
#pragma unroll
        for (int r = 0; r < 4; r++) {
            int row = m0 + wr * 64 + mi * 16 + quad * 4 + r;
            size_t base = (size_t)row * N;
#pragma unroll
            for (int ni = 0; ni < 4; ni++) {
                int col = n0 + wc * 64 + ni * 16 + l15;
                float v = acc[mi][ni][r] + bias_v[ni];
                if (EPI == 2) v = 0.5f * v * (1.f + erff(v * 0.70710678118f));
                if (EPI == 1 || EPI == 3) v += ldf(res + base + col);
                stf(out + base + col, v);
            }
        }
    }
}

// =====================================================================
// Flash distance-attention, MFMA version.
// score(q,k) = -softplus(gamma_h) * max(|zq-zk|^2, 0)   (coords bf16)
// Block = 256 thr (4 waves); Q-tile = 64 (wave w owns rows w*16..+16).
// K-loop: 64-key tiles. QK^T: 4x mfma_16x16x32 (coords padded 16->32).
// Online softmax on the D-layout (row=quad*4+r, col=lane&15).
// P -> wave-private LDS -> PV: 8x mfma (V transposed in LDS at staging).
// grid = (B*H = 32, S/64 = 32)
// =====================================================================
__global__ __launch_bounds__(256) void attn2_kernel(const float* __restrict__ zh,
                                                    const USH* __restrict__ value,
                                                    const float* __restrict__ gamma,
                                                    USH* __restrict__ attn_out) {
    int b = blockIdx.x >> 4, h = blockIdx.x & 15;
    int q0 = blockIdx.y * 64;
    int tid = threadIdx.x, lane = tid & 63, wq = tid >> 6;
    int quad = lane >> 4, l15 = lane & 15;

    __shared__ __align__(16) USH Qb[64][40];    // [q][coord 0..32), pads zero
    __shared__ __align__(16) USH KbT[64][40];   // [k][coord 0..32), pads zero
    __shared__ __align__(16) USH VbT[64][72];   // [dh][key]
    __shared__ __align__(16) USH Pb[4][16][72]; // per-wave P [q][key]
    __shared__ float Qs[64], Ks[64];

    // zero the k-pad region [16,32) once (never rewritten)
    for (int i = tid; i < 64 * 16; i += 256) {
        Qb[i >> 4][16 + (i & 15)] = 0;
        KbT[i >> 4][16 + (i & 15)] = 0;
    }

    const size_t zbase = (size_t)b * 2048 * 256 + h * 16;
    const size_t vbase = (size_t)b * 2048 * 1024 + h * 64;

    // ---- stage Q tile + Qs (sumsq of bf16-rounded coords) ----
    {
        int q = tid >> 2, c0 = (tid & 3) * 4;
        float4 v = *(const float4*)(zh + zbase + (size_t)(q0 + q) * 256 + c0);
        USH u0 = f2b(v.x), u1 = f2b(v.y), u2 = f2b(v.z), u3 = f2b(v.w);
        Qb[q][c0] = u0; Qb[q][c0 + 1] = u1; Qb[q][c0 + 2] = u2; Qb[q][c0 + 3] = u3;
        float f0 = b2f(u0), f1 = b2f(u1), f2v = b2f(u2), f3 = b2f(u3);
        float part = f0 * f0 + f1 * f1 + f2v * f2v + f3 * f3;
        part += __shfl_xor(part, 1);
        part += __shfl_xor(part, 2);
        if ((tid & 3) == 0) Qs[q] = part;
    }
    __syncthreads();

    bf16x8 afragQ = *(const bf16x8*)&Qb[wq * 16 + l15][quad * 8];
    float gv;
    { float gx = gamma[h]; gv = log1pf(__expf(gx)); }  // softplus

    floatx4 oacc[4] = {};
    float mr[4], lr[4];
#pragma unroll
    for (int r = 0; r < 4; r++) { mr[r] = -1e30f; lr[r] = 0.f; }

    for (int kt = 0; kt < 2048; kt += 64) {
        __syncthreads();
        {   // stage K tile + Ks
            int k = tid >> 2, c0 = (tid & 3) * 4;
            float4 v = *(const float4*)(zh + zbase + (size_t)(kt + k) * 256 + c0);
            USH u0 = f2b(v.x), u1 = f2b(v.y), u2 = f2b(v.z), u3 = f2b(v.w);
            KbT[k][c0] = u0; KbT[k][c0 + 1] = u1; KbT[k][c0 + 2] = u2; KbT[k][c0 + 3] = u3;
            float f0 = b2f(u0), f1 = b2f(u1), f2v = b2f(u2), f3 = b2f(u3);
            float part = f0 * f0 + f1 * f1 + f2v * f2v + f3 * f3;
            part += __shfl_xor(part, 1);
            part += __shfl_xor(part, 2);
            if ((tid & 3) == 0) Ks[k] = part;
        }
        {   // stage V transposed: VbT[dh][key]
            int k = tid >> 2, cc = tid & 3;
#pragma unroll
            for (int rnd = 0; rnd < 2; rnd++) {
                int dh0 = (cc + rnd * 4) * 8;
                int4 t = *(const int4*)(value + vbase + (size_t)(kt + k) * 1024 + dh0);
                const USH* u = (const USH*)&t;
#pragma unroll
                for (int e = 0; e < 8; e++) VbT[dh0 + e][k] = u[e];
            }
        }
        __syncthreads();

        // ---- QK^T ----
        floatx4 sacc[4];
#pragma unroll
        for (int ni = 0; ni < 4; ni++) {
            bf16x8 bk = *(const bf16x8*)&KbT[ni * 16 + l15][quad * 8];
            floatx4 zacc = {};
            sacc[ni] = __builtin_amdgcn_mfma_f32_16x16x32_bf16(afragQ, bk, zacc, 0, 0, 0);
        }
        float ksv[4];
#pragma unroll
        for (int ni = 0; ni < 4; ni++) ksv[ni] = Ks[ni * 16 + l15];

        float sc[4][4];
#pragma unroll
        for (int r = 0; r < 4; r++) {
            float qs = Qs[wq * 16 + quad * 4 + r];
#pragma unroll
            for (int ni = 0; ni < 4; ni++) {
                float d = fmaxf(qs + ksv[ni] - 2.f * sacc[ni][r], 0.f);
                sc[ni][r] = -gv * d;
            }
        }

        // ---- online softmax per q-row ----
#pragma unroll
        for (int r = 0; r < 4; r++) {
            float rm = fmaxf(fmaxf(sc[0][r], sc[1][r]), fmaxf(sc[2][r], sc[3][r]));
            rm = fmaxf(rm, __shfl_xor(rm, 1));
            rm = fmaxf(rm, __shfl_xor(rm, 2));
            rm = fmaxf(rm, __shfl_xor(rm, 4));
            rm = fmaxf(rm, __shfl_xor(rm, 8));
            float nm = fmaxf(mr[r], rm);
            float alpha = __expf(mr[r] - nm);
            mr[r] = nm;
            float ps = 0.f;
#pragma unroll
            for (int ni = 0; ni < 4; ni++) {
                float p = __expf(sc[ni][r] - nm);
                ps += p;
                Pb[wq][quad * 4 + r][ni * 16 + l15] = f2b(p);
            }
            ps += __shfl_xor(ps, 1);
            ps += __shfl_xor(ps, 2);
            ps += __shfl_xor(ps, 4);
            ps += __shfl_xor(ps, 8);
            lr[r] = lr[r] * alpha + ps;
#pragma unroll
            for (int nd = 0; nd < 4; nd++) oacc[nd][r] *= alpha;
        }

        // ---- PV (Pb is wave-private: same-wave LDS ops are in-order) ----
#pragma unroll
        for (int ks = 0; ks < 2; ks++) {
            bf16x8 ap = *(const bf16x8*)&Pb[wq][l15][ks * 32 + quad * 8];
#pragma unroll
            for (int nd = 0; nd < 4; nd++) {
                bf16x8 bv = *(const bf16x8*)&VbT[nd * 16 + l15][ks * 32 + quad * 8];
                oacc[nd] = __builtin_amdgcn_mfma_f32_16x16x32_bf16(ap, bv, oacc[nd], 0, 0, 0);
            }
        }
    }

    // ---- epilogue ----
#pragma unroll
    for (int r = 0; r < 4; r++) {
        float inv = 1.f / lr[r];
        int row = q0 + wq * 16 + quad * 4 + r;
        USH* o = attn_out + ((size_t)(b * 2048 + row)) * 1024 + h * 64;
#pragma unroll
        for (int nd = 0; nd < 4; nd++) o[nd * 16 + l15] = f2b(oacc[nd][r] * inv);
    }
}

// =====================================================================
// z_out = LN(z + z_next) over rows of 64. block = 64 (one wave) per row.
// All f32.
// =====================================================================
__global__ __launch_bounds__(64) void lnc_kernel(const float* __restrict__ z,
                                                 const float* __restrict__ zn,
                                                 const float* __restrict__ g,
                                                 const float* __restrict__ bb,
                                                 float* __restrict__ out) {
    int row = blockIdx.x, t = threadIdx.x;
    float v = z[(size_t)row * 64 + t] + zn[(size_t)row * 64 + t];
    float s = v, ss = v * v;
#pragma unroll
    for (int o = 32; o; o >>= 1) { s += __shfl_xor(s, o); ss += __shfl_xor(ss, o); }
    float mean = s * (1.f / 64.f);
    float rstd = rsqrtf(ss * (1.f / 64.f) - mean * mean + 1e-5f);
    out[(size_t)row * 64 + t] = (v - mean) * rstd * g[t] + bb[t];
}

// =====================================================================
extern "C" void kernel_launch(void* const* d_in, const int* in_sizes, int n_in,
                              void* d_out, int out_size, void* d_ws, size_t ws_size,
                              hipStream_t stream) {
    // workspace layout (49 MB) -- identical to the R2-validated layout:
    //   [0,8M)    value (bf16)       -- dead after attn
    //   [8M,16M)  attn_o (bf16)      -- dead after wo-gemm
    //   [16M,20M) zh (f32)           -- dead after attn
    //   [20M,28M) hn (bf16)          -- dead after znext
    //   [0,32M)   mid (bf16)         -- overlays the four above (written step 8)
    //   [32M,40M) hn2 (bf16)
    //   [40M,48M) h1 (bf16)
    //   [48M,49M) znext (f32)
    char* p = (char*)d_ws;
    USH*   value  = (USH*)(p);
    USH*   attn_o = (USH*)(p + ((size_t)8  << 20));
    float* zh     = (float*)(p + ((size_t)16 << 20));
    USH*   hn     = (USH*)(p + ((size_t)20 << 20));
    USH*   mid    = (USH*)(p);
    USH*   hn2    = (USH*)(p + ((size_t)32 << 20));
    USH*   h1     = (USH*)(p + ((size_t)40 << 20));
    float* znext  = (float*)(p + ((size_t)48 << 20));

    // inputs are float32 (verified: R2's runtime-dispatch pass took the f32
    // path; hardcoded-bf16 R3 NaN'd -- f32-bytes-as-bf16 makes Inf/NaN)
    const float *h    = (const float*)d_in[0],  *z    = (const float*)d_in[1];
    const float *wv   = (const float*)d_in[2],  *bv   = (const float*)d_in[3];
    const float *wca  = (const float*)d_in[4],  *bca  = (const float*)d_in[5];
    const float *wcn  = (const float*)d_in[6],  *bcn  = (const float*)d_in[7];
    const float *wo   = (const float*)d_in[8],  *bo   = (const float*)d_in[9];
    const float *gam  = (const float*)d_in[10];
    const float *w1   = (const float*)d_in[11], *b1   = (const float*)d_in[12];
    const float *w2   = (const float*)d_in[13], *b2   = (const float*)d_in[14];
    const float *ln1g = (const float*)d_in[15], *ln1b = (const float*)d_in[16];
    const float *ln2g = (const float*)d_in[17], *ln2b = (const float*)d_in[18];
    const float *lncg = (const float*)d_in[19], *lncb = (const float*)d_in[20];

    float* out_h = (float*)d_out;
    float* out_z = out_h + (size_t)4096 * 1024;

    // 1. hn = LN1(h)                         (f32 in, bf16 ws out)
    ln_rows<float><<<4096, 256, 0, stream>>>(h, ln1g, ln1b, hn);
    // 2. zh = z @ wca + bca                  (f32)
    zh_kernel<<<4096, 256, 0, stream>>>(z, wca, bca, zh);
    // 3. value = hn @ wv + bv
    gemm_kernel<0, USH, USH><<<dim3(8, 32), 256, 0, stream>>>(hn, wv, bv, (const USH*)nullptr, value, 4096, 1024, 1024);
    // 4. z_next = hn @ wcn + bcn
    znext_kernel<<<4096, 256, 0, stream>>>(hn, wcn, bcn, znext);
    // 5. attention (MFMA flash)
    attn2_kernel<<<dim3(32, 32), 256, 0, stream>>>(zh, value, gam, attn_o);
    // 6. h1 = h + attn_o @ wo + bo           (res f32, out bf16 ws)
    gemm_kernel<1, float, USH><<<dim3(8, 32), 256, 0, stream>>>(attn_o, wo, bo, h, h1, 4096, 1024, 1024);
    // 7. hn2 = LN2(h1)                       (bf16 ws in)
    ln_rows<USH><<<4096, 256, 0, stream>>>(h1, ln2g, ln2b, hn2);
    // 8. mid = gelu(hn2 @ w1 + b1)           (overlays value/attn_o/zh/hn)
    gemm_kernel<2, USH, USH><<<dim3(32, 32), 256, 0, stream>>>(hn2, w1, b1, (const USH*)nullptr, mid, 4096, 4096, 1024);
    // 9. out_h = h1 + mid @ w2 + b2          (res bf16 ws, out f32)
    gemm_kernel<3, USH, float><<<dim3(8, 32), 256, 0, stream>>>(mid, w2, b2, h1, out_h, 4096, 1024, 4096);
    // 10. out_z = LN(z + znext)              (f32)
    lnc_kernel<<<4096, 64, 0, stream>>>(z, znext, lncg, lncb, out_z);
}

// Round 5
// 558.516 us; speedup vs baseline: 2.7723x; 1.5436x over previous
//
#include <hip/hip_runtime.h>

#define USH unsigned short

// ---------- bf16 helpers (storage = unsigned short) ----------
__device__ __forceinline__ float b2f(USH u) {
    union { unsigned int i; float f; } x; x.i = ((unsigned int)u) << 16; return x.f;
}
__device__ __forceinline__ USH f2b(float f) {
    union { float f; unsigned int i; } x; x.f = f;
    unsigned int r = x.i + (0x7fffu + ((x.i >> 16) & 1u));  // RNE
    return (USH)(r >> 16);
}
__device__ __forceinline__ float ldf(const USH* p)  { return b2f(*p); }
__device__ __forceinline__ float ldf(const float* p){ return *p; }
__device__ __forceinline__ void stf(USH* p, float v)  { *p = f2b(v); }
__device__ __forceinline__ void stf(float* p, float v){ *p = v; }

typedef __attribute__((ext_vector_type(8))) __bf16 bf16x8;
typedef __attribute__((ext_vector_type(4))) float  floatx4;

// =====================================================================
// Weight transpose+convert: W[K][N] f32 -> WT[N][K] bf16.
// 64x64 tiles, grid (N/64, K/64), block 256.
// =====================================================================
__global__ __launch_bounds__(256) void transpose_f2b(const float* __restrict__ W,
                                                     USH* __restrict__ WT,
                                                     int K, int N) {
    __shared__ USH t[64][72];
    int n0 = blockIdx.x * 64, k0 = blockIdx.y * 64;
    int tid = threadIdx.x;
    int kr = tid >> 4, nc = (tid & 15) * 4;
#pragma unroll
    for (int r = 0; r < 4; r++) {
        int k = kr + r * 16;
        float4 v = *(const float4*)(W + (size_t)(k0 + k) * N + n0 + nc);
        t[nc + 0][k] = f2b(v.x); t[nc + 1][k] = f2b(v.y);
        t[nc + 2][k] = f2b(v.z); t[nc + 3][k] = f2b(v.w);
    }
    __syncthreads();
    int nr = tid >> 2, kc = (tid & 3) * 8;
#pragma unroll
    for (int r = 0; r < 2; r++) {
        int k = kc + r * 32;
        *(int4*)(WT + (size_t)(n0 + nr) * K + k0 + k) = *(const int4*)&t[nr][k];
    }
}

// =====================================================================
// LayerNorm rows of 1024. block=256, one block/row. TX = f32 or bf16(ws).
// Params f32 (d_in). Output bf16 (ws).
// =====================================================================
template <typename TX>
__global__ __launch_bounds__(256) void ln_rows(const TX* __restrict__ x,
                                               const float* __restrict__ g,
                                               const float* __restrict__ bb,
                                               USH* __restrict__ y) {
    int row = blockIdx.x, tid = threadIdx.x;
    const TX* xr = x + (size_t)row * 1024 + tid * 4;
    float v[4];
#pragma unroll
    for (int i = 0; i < 4; i++) v[i] = ldf(xr + i);
    float s  = v[0] + v[1] + v[2] + v[3];
    float ss = v[0]*v[0] + v[1]*v[1] + v[2]*v[2] + v[3]*v[3];
#pragma unroll
    for (int o = 32; o; o >>= 1) { s += __shfl_down(s, o); ss += __shfl_down(ss, o); }
    __shared__ float red[10];
    int w = tid >> 6;
    if ((tid & 63) == 0) { red[w] = s; red[4 + w] = ss; }
    __syncthreads();
    if (tid == 0) {
        float S = red[0] + red[1] + red[2] + red[3];
        float SS = red[4] + red[5] + red[6] + red[7];
        float mean = S * (1.f / 1024.f);
        float var  = SS * (1.f / 1024.f) - mean * mean;
        red[8] = mean; red[9] = rsqrtf(var + 1e-5f);
    }
    __syncthreads();
    float mean = red[8], rstd = red[9];
    USH* yr = y + (size_t)row * 1024 + tid * 4;
#pragma unroll
    for (int i = 0; i < 4; i++) {
        int c = tid * 4 + i;
        yr[i] = f2b((v[i] - mean) * rstd * g[c] + bb[c]);
    }
}

// =====================================================================
// zh = z @ wca + bca   (4096 rows, K=64, N=256) f32 in -> f32 out (ws)
// =====================================================================
__global__ __launch_bounds__(256) void zh_kernel(const float* __restrict__ z,
                                                 const float* __restrict__ wca,
                                                 const float* __restrict__ bca,
                                                 float* __restrict__ zh) {
    int row = blockIdx.x, n = threadIdx.x;
    __shared__ float zrow[64];
    if (n < 64) zrow[n] = z[(size_t)row * 64 + n];
    __syncthreads();
    float s = bca[n];
#pragma unroll 8
    for (int k = 0; k < 64; k++) s = fmaf(zrow[k], wca[(size_t)k * 256 + n], s);
    zh[(size_t)row * 256 + n] = s;
}

// =====================================================================
// z_next = hn(bf16 ws) @ wcn(f32) + bcn  (4096 rows, K=1024, N=64) -> f32
// =====================================================================
__global__ __launch_bounds__(256) void znext_kernel(const USH* __restrict__ hn,
                                                    const float* __restrict__ wcn,
                                                    const float* __restrict__ bcn,
                                                    float* __restrict__ zn) {
    int row = blockIdx.x, t = threadIdx.x;
    int n = t & 63, ks = t >> 6;
    const USH* a = hn + (size_t)row * 1024 + ks * 256;
    const float* w = wcn + (size_t)ks * 256 * 64 + n;
    float s = 0.f;
#pragma unroll 4
    for (int k = 0; k < 256; k++) s = fmaf(b2f(a[k]), w[(size_t)k * 64], s);
    __shared__ float part[4][64];
    part[ks][n] = s;
    __syncthreads();
    if (t < 64)
        zn[(size_t)row * 64 + t] = part[0][t] + part[1][t] + part[2][t] + part[3][t] + bcn[t];
}

// =====================================================================
// MFMA GEMM: C[M,N] = A[M,K](bf16) @ WT[N][K](bf16) + bias(f32)
// Tile BM x 128, BM = MI*32 (MI=4 -> 128, MI=2 -> 64). 4 waves, BK=32.
// Wave (wr,wc) owns rows wr*(MI*16)+mi*16, cols wc*64+ni*16.
// EPI: 0 = plain | 1 = +res | 2 = gelu | 3 = +res
// =====================================================================
template <int EPI, int MI, typename TRES, typename TOUT>
__global__ __launch_bounds__(256) void gemm_kernel(const USH* __restrict__ A,
                                                   const USH* __restrict__ WT,
                                                   const float* __restrict__ bias,
                                                   const TRES* __restrict__ res,
                                                   TOUT* __restrict__ out,
                                                   int M, int N, int K) {
    constexpr int BM = MI * 32;
    __shared__ __align__(16) USH lA[BM][40];   // [m][k], pad 32->40
    __shared__ __align__(16) USH lB[128][40];  // [n][k]
    int tid = threadIdx.x;
    int lane = tid & 63, wave = tid >> 6;
    int wr = wave >> 1, wc = wave & 1;
    int quad = lane >> 4, l15 = lane & 15;
    int m0 = blockIdx.y * BM, n0 = blockIdx.x * 128;

    int s_row = tid >> 2, s_k = (tid & 3) * 8;

    floatx4 acc[MI][4] = {};

    for (int k0 = 0; k0 < K; k0 += 32) {
#pragma unroll
        for (int r = 0; r < BM / 64; r++) {
            int row = s_row + r * 64;
            *(int4*)&lA[row][s_k] = *(const int4*)(A + (size_t)(m0 + row) * K + k0 + s_k);
        }
#pragma unroll
        for (int r = 0; r < 2; r++) {
            int row = s_row + r * 64;
            *(int4*)&lB[row][s_k] = *(const int4*)(WT + (size_t)(n0 + row) * K + k0 + s_k);
        }
        __syncthreads();
        bf16x8 bfr[4];
#pragma unroll
        for (int ni = 0; ni < 4; ni++)
            bfr[ni] = *(const bf16x8*)&lB[wc * 64 + ni * 16 + l15][quad * 8];
#pragma unroll
        for (int mi = 0; mi < MI; mi++) {
            bf16x8 afr = *(const bf16x8*)&lA[wr * (MI * 16) + mi * 16 + l15][quad * 8];
#pragma unroll
            for (int ni = 0; ni < 4; ni++)
                acc[mi][ni] = __builtin_amdgcn_mfma_f32_16x16x32_bf16(afr, bfr[ni], acc[mi][ni], 0, 0, 0);
        }
        __syncthreads();
    }

    float bias_v[4];
#pragma unroll
    for (int ni = 0; ni < 4; ni++) bias_v[ni] = bias[n0 + wc * 64 + ni * 16 + l15];

#pragma unroll
    for (int mi = 0; mi < MI; mi++) {
#pragma unroll
        for (int r = 0; r < 4; r++) {
            int row = m0 + wr * (MI * 16) + mi * 16 + quad * 4 + r;
            size_t base = (size_t)row * N;
#pragma unroll
            for (int ni = 0; ni < 4; ni++) {
                int col = n0 + wc * 64 + ni * 16 + l15;
                float v = acc[mi][ni][r] + bias_v[ni];
                if (EPI == 2) v = 0.5f * v * (1.f + erff(v * 0.70710678118f));
                if (EPI == 1 || EPI == 3) v += ldf(res + base + col);
                stf(out + base + col, v);
            }
        }
    }
}

// =====================================================================
// Flash distance-attention, MFMA (unchanged from R4 -- validated).
// =====================================================================
__global__ __launch_bounds__(256) void attn2_kernel(const float* __restrict__ zh,
                                                    const USH* __restrict__ value,
                                                    const float* __restrict__ gamma,
                                                    USH* __restrict__ attn_out) {
    int b = blockIdx.x >> 4, h = blockIdx.x & 15;
    int q0 = blockIdx.y * 64;
    int tid = threadIdx.x, lane = tid & 63, wq = tid >> 6;
    int quad = lane >> 4, l15 = lane & 15;

    __shared__ __align__(16) USH Qb[64][40];
    __shared__ __align__(16) USH KbT[64][40];
    __shared__ __align__(16) USH VbT[64][72];
    __shared__ __align__(16) USH Pb[4][16][72];
    __shared__ float Qs[64], Ks[64];

    for (int i = tid; i < 64 * 16; i += 256) {
        Qb[i >> 4][16 + (i & 15)] = 0;
        KbT[i >> 4][16 + (i & 15)] = 0;
    }

    const size_t zbase = (size_t)b * 2048 * 256 + h * 16;
    const size_t vbase = (size_t)b * 2048 * 1024 + h * 64;

    {
        int q = tid >> 2, c0 = (tid & 3) * 4;
        float4 v = *(const float4*)(zh + zbase + (size_t)(q0 + q) * 256 + c0);
        USH u0 = f2b(v.x), u1 = f2b(v.y), u2 = f2b(v.z), u3 = f2b(v.w);
        Qb[q][c0] = u0; Qb[q][c0 + 1] = u1; Qb[q][c0 + 2] = u2; Qb[q][c0 + 3] = u3;
        float f0 = b2f(u0), f1 = b2f(u1), f2v = b2f(u2), f3 = b2f(u3);
        float part = f0 * f0 + f1 * f1 + f2v * f2v + f3 * f3;
        part += __shfl_xor(part, 1);
        part += __shfl_xor(part, 2);
        if ((tid & 3) == 0) Qs[q] = part;
    }
    __syncthreads();

    bf16x8 afragQ = *(const bf16x8*)&Qb[wq * 16 + l15][quad * 8];
    float gv;
    { float gx = gamma[h]; gv = log1pf(__expf(gx)); }

    floatx4 oacc[4] = {};
    float mr[4], lr[4];
#pragma unroll
    for (int r = 0; r < 4; r++) { mr[r] = -1e30f; lr[r] = 0.f; }

    for (int kt = 0; kt < 2048; kt += 64) {
        __syncthreads();
        {
            int k = tid >> 2, c0 = (tid & 3) * 4;
            float4 v = *(const float4*)(zh + zbase + (size_t)(kt + k) * 256 + c0);
            USH u0 = f2b(v.x), u1 = f2b(v.y), u2 = f2b(v.z), u3 = f2b(v.w);
            KbT[k][c0] = u0; KbT[k][c0 + 1] = u1; KbT[k][c0 + 2] = u2; KbT[k][c0 + 3] = u3;
            float f0 = b2f(u0), f1 = b2f(u1), f2v = b2f(u2), f3 = b2f(u3);
            float part = f0 * f0 + f1 * f1 + f2v * f2v + f3 * f3;
            part += __shfl_xor(part, 1);
            part += __shfl_xor(part, 2);
            if ((tid & 3) == 0) Ks[k] = part;
        }
        {
            int k = tid >> 2, cc = tid & 3;
#pragma unroll
            for (int rnd = 0; rnd < 2; rnd++) {
                int dh0 = (cc + rnd * 4) * 8;
                int4 t = *(const int4*)(value + vbase + (size_t)(kt + k) * 1024 + dh0);
                const USH* u = (const USH*)&t;
#pragma unroll
                for (int e = 0; e < 8; e++) VbT[dh0 + e][k] = u[e];
            }
        }
        __syncthreads();

        floatx4 sacc[4];
#pragma unroll
        for (int ni = 0; ni < 4; ni++) {
            bf16x8 bk = *(const bf16x8*)&KbT[ni * 16 + l15][quad * 8];
            floatx4 zacc = {};
            sacc[ni] = __builtin_amdgcn_mfma_f32_16x16x32_bf16(afragQ, bk, zacc, 0, 0, 0);
        }
        float ksv[4];
#pragma unroll
        for (int ni = 0; ni < 4; ni++) ksv[ni] = Ks[ni * 16 + l15];

        float sc[4][4];
#pragma unroll
        for (int r = 0; r < 4; r++) {
            float qs = Qs[wq * 16 + quad * 4 + r];
#pragma unroll
            for (int ni = 0; ni < 4; ni++) {
                float d = fmaxf(qs + ksv[ni] - 2.f * sacc[ni][r], 0.f);
                sc[ni][r] = -gv * d;
            }
        }

#pragma unroll
        for (int r = 0; r < 4; r++) {
            float rm = fmaxf(fmaxf(sc[0][r], sc[1][r]), fmaxf(sc[2][r], sc[3][r]));
            rm = fmaxf(rm, __shfl_xor(rm, 1));
            rm = fmaxf(rm, __shfl_xor(rm, 2));
            rm = fmaxf(rm, __shfl_xor(rm, 4));
            rm = fmaxf(rm, __shfl_xor(rm, 8));
            float nm = fmaxf(mr[r], rm);
            float alpha = __expf(mr[r] - nm);
            mr[r] = nm;
            float ps = 0.f;
#pragma unroll
            for (int ni = 0; ni < 4; ni++) {
                float p = __expf(sc[ni][r] - nm);
                ps += p;
                Pb[wq][quad * 4 + r][ni * 16 + l15] = f2b(p);
            }
            ps += __shfl_xor(ps, 1);
            ps += __shfl_xor(ps, 2);
            ps += __shfl_xor(ps, 4);
            ps += __shfl_xor(ps, 8);
            lr[r] = lr[r] * alpha + ps;
#pragma unroll
            for (int nd = 0; nd < 4; nd++) oacc[nd][r] *= alpha;
        }

#pragma unroll
        for (int ks = 0; ks < 2; ks++) {
            bf16x8 ap = *(const bf16x8*)&Pb[wq][l15][ks * 32 + quad * 8];
#pragma unroll
            for (int nd = 0; nd < 4; nd++) {
                bf16x8 bv = *(const bf16x8*)&VbT[nd * 16 + l15][ks * 32 + quad * 8];
                oacc[nd] = __builtin_amdgcn_mfma_f32_16x16x32_bf16(ap, bv, oacc[nd], 0, 0, 0);
            }
        }
    }

#pragma unroll
    for (int r = 0; r < 4; r++) {
        float inv = 1.f / lr[r];
        int row = q0 + wq * 16 + quad * 4 + r;
        USH* o = attn_out + ((size_t)(b * 2048 + row)) * 1024 + h * 64;
#pragma unroll
        for (int nd = 0; nd < 4; nd++) o[nd * 16 + l15] = f2b(oacc[nd][r] * inv);
    }
}

// =====================================================================
// z_out = LN(z + z_next) over rows of 64. block = 64 (one wave) per row.
// =====================================================================
__global__ __launch_bounds__(64) void lnc_kernel(const float* __restrict__ z,
                                                 const float* __restrict__ zn,
                                                 const float* __restrict__ g,
                                                 const float* __restrict__ bb,
                                                 float* __restrict__ out) {
    int row = blockIdx.x, t = threadIdx.x;
    float v = z[(size_t)row * 64 + t] + zn[(size_t)row * 64 + t];
    float s = v, ss = v * v;
#pragma unroll
    for (int o = 32; o; o >>= 1) { s += __shfl_xor(s, o); ss += __shfl_xor(ss, o); }
    float mean = s * (1.f / 64.f);
    float rstd = rsqrtf(ss * (1.f / 64.f) - mean * mean + 1e-5f);
    out[(size_t)row * 64 + t] = (v - mean) * rstd * g[t] + bb[t];
}

// =====================================================================
extern "C" void kernel_launch(void* const* d_in, const int* in_sizes, int n_in,
                              void* d_out, int out_size, void* d_ws, size_t ws_size,
                              hipStream_t stream) {
    // workspace layout (61 MB):
    //   [0,8M)    value (bf16)       -- dead after attn
    //   [8,16M)   attn_o (bf16)      -- dead after wo-gemm
    //   [16,20M)  zh (f32)           -- dead after attn
    //   [20,28M)  hn (bf16)          -- dead after znext
    //   [0,32M)   mid (bf16)         -- overlays the four above (written step 8)
    //   [32,40M)  hn2 (bf16)
    //   [40,41M)  znext (f32)
    //   [41,43M)  wvT (bf16 [1024][1024])
    //   [43,45M)  woT (bf16 [1024][1024])
    //   [45,53M)  w1T (bf16 [4096][1024])
    //   [53,61M)  w2T (bf16 [1024][4096])
    // h1 (f32) lives in d_out's h region (read-modify-write in step 9 is
    // same-thread same-index, safe).
    char* p = (char*)d_ws;
    USH*   value  = (USH*)(p);
    USH*   attn_o = (USH*)(p + ((size_t)8  << 20));
    float* zh     = (float*)(p + ((size_t)16 << 20));
    USH*   hn     = (USH*)(p + ((size_t)20 << 20));
    USH*   mid    = (USH*)(p);
    USH*   hn2    = (USH*)(p + ((size_t)32 << 20));
    float* znext  = (float*)(p + ((size_t)40 << 20));
    USH*   wvT    = (USH*)(p + ((size_t)41 << 20));
    USH*   woT    = (USH*)(p + ((size_t)43 << 20));
    USH*   w1T    = (USH*)(p + ((size_t)45 << 20));
    USH*   w2T    = (USH*)(p + ((size_t)53 << 20));

    const float *h    = (const float*)d_in[0],  *z    = (const float*)d_in[1];
    const float *wv   = (const float*)d_in[2],  *bv   = (const float*)d_in[3];
    const float *wca  = (const float*)d_in[4],  *bca  = (const float*)d_in[5];
    const float *wcn  = (const float*)d_in[6],  *bcn  = (const float*)d_in[7];
    const float *wo   = (const float*)d_in[8],  *bo   = (const float*)d_in[9];
    const float *gam  = (const float*)d_in[10];
    const float *w1   = (const float*)d_in[11], *b1   = (const float*)d_in[12];
    const float *w2   = (const float*)d_in[13], *b2   = (const float*)d_in[14];
    const float *ln1g = (const float*)d_in[15], *ln1b = (const float*)d_in[16];
    const float *ln2g = (const float*)d_in[17], *ln2b = (const float*)d_in[18];
    const float *lncg = (const float*)d_in[19], *lncb = (const float*)d_in[20];

    float* out_h = (float*)d_out;
    float* out_z = out_h + (size_t)4096 * 1024;
    float* h1    = out_h;   // f32 h1 lives in the output buffer

    // 0. weight conversion (f32 [K][N] -> bf16 [N][K])
    transpose_f2b<<<dim3(16, 16), 256, 0, stream>>>(wv, wvT, 1024, 1024);
    transpose_f2b<<<dim3(16, 16), 256, 0, stream>>>(wo, woT, 1024, 1024);
    transpose_f2b<<<dim3(64, 16), 256, 0, stream>>>(w1, w1T, 1024, 4096);
    transpose_f2b<<<dim3(16, 64), 256, 0, stream>>>(w2, w2T, 4096, 1024);

    // 1. hn = LN1(h)
    ln_rows<float><<<4096, 256, 0, stream>>>(h, ln1g, ln1b, hn);
    // 2. zh = z @ wca + bca
    zh_kernel<<<4096, 256, 0, stream>>>(z, wca, bca, zh);
    // 3. value = hn @ wv + bv          (M=4096,N=1024,K=1024; 512 blocks)
    gemm_kernel<0, 2, USH, USH><<<dim3(8, 64), 256, 0, stream>>>(hn, wvT, bv, (const USH*)nullptr, value, 4096, 1024, 1024);
    // 4. z_next = hn @ wcn + bcn
    znext_kernel<<<4096, 256, 0, stream>>>(hn, wcn, bcn, znext);
    // 5. attention (MFMA flash)
    attn2_kernel<<<dim3(32, 32), 256, 0, stream>>>(zh, value, gam, attn_o);
    // 6. h1 = h + attn_o @ wo + bo     (out f32 -> d_out h-region)
    gemm_kernel<1, 2, float, float><<<dim3(8, 64), 256, 0, stream>>>(attn_o, woT, bo, h, h1, 4096, 1024, 1024);
    // 7. hn2 = LN2(h1)
    ln_rows<float><<<4096, 256, 0, stream>>>(h1, ln2g, ln2b, hn2);
    // 8. mid = gelu(hn2 @ w1 + b1)     (M=4096,N=4096,K=1024; 1024 blocks)
    gemm_kernel<2, 4, USH, USH><<<dim3(32, 32), 256, 0, stream>>>(hn2, w1T, b1, (const USH*)nullptr, mid, 4096, 4096, 1024);
    // 9. out_h = h1 + mid @ w2 + b2    (res==out aliasing is same-thread)
    gemm_kernel<3, 2, float, float><<<dim3(8, 64), 256, 0, stream>>>(mid, w2T, b2, h1, out_h, 4096, 1024, 4096);
    // 10. out_z = LN(z + znext)
    lnc_kernel<<<4096, 64, 0, stream>>>(z, znext, lncg, lncb, out_z);
}

// Round 6
// 496.138 us; speedup vs baseline: 3.1209x; 1.1257x over previous
//
#include <hip/hip_runtime.h>

#define USH unsigned short

// ---------- bf16 helpers (storage = unsigned short) ----------
__device__ __forceinline__ float b2f(USH u) {
    union { unsigned int i; float f; } x; x.i = ((unsigned int)u) << 16; return x.f;
}
__device__ __forceinline__ USH f2b(float f) {
    union { float f; unsigned int i; } x; x.f = f;
    unsigned int r = x.i + (0x7fffu + ((x.i >> 16) & 1u));  // RNE
    return (USH)(r >> 16);
}
__device__ __forceinline__ float ldf(const USH* p)  { return b2f(*p); }
__device__ __forceinline__ float ldf(const float* p){ return *p; }
__device__ __forceinline__ void stf(USH* p, float v)  { *p = f2b(v); }
__device__ __forceinline__ void stf(float* p, float v){ *p = v; }

typedef __attribute__((ext_vector_type(8))) __bf16 bf16x8;
typedef __attribute__((ext_vector_type(4))) float  floatx4;

// =====================================================================
// Weight transpose+convert: W[K][N] f32 -> WT[N][K] bf16.
// 64x64 tiles, grid (N/64, K/64), block 256.
// =====================================================================
__global__ __launch_bounds__(256) void transpose_f2b(const float* __restrict__ W,
                                                     USH* __restrict__ WT,
                                                     int K, int N) {
    __shared__ USH t[64][72];
    int n0 = blockIdx.x * 64, k0 = blockIdx.y * 64;
    int tid = threadIdx.x;
    int kr = tid >> 4, nc = (tid & 15) * 4;
#pragma unroll
    for (int r = 0; r < 4; r++) {
        int k = kr + r * 16;
        float4 v = *(const float4*)(W + (size_t)(k0 + k) * N + n0 + nc);
        t[nc + 0][k] = f2b(v.x); t[nc + 1][k] = f2b(v.y);
        t[nc + 2][k] = f2b(v.z); t[nc + 3][k] = f2b(v.w);
    }
    __syncthreads();
    int nr = tid >> 2, kc = (tid & 3) * 8;
#pragma unroll
    for (int r = 0; r < 2; r++) {
        int k = kc + r * 32;
        *(int4*)(WT + (size_t)(n0 + nr) * K + k0 + k) = *(const int4*)&t[nr][k];
    }
}

// =====================================================================
// LayerNorm rows of 1024. block=256, one block/row.
// =====================================================================
template <typename TX>
__global__ __launch_bounds__(256) void ln_rows(const TX* __restrict__ x,
                                               const float* __restrict__ g,
                                               const float* __restrict__ bb,
                                               USH* __restrict__ y) {
    int row = blockIdx.x, tid = threadIdx.x;
    const TX* xr = x + (size_t)row * 1024 + tid * 4;
    float v[4];
#pragma unroll
    for (int i = 0; i < 4; i++) v[i] = ldf(xr + i);
    float s  = v[0] + v[1] + v[2] + v[3];
    float ss = v[0]*v[0] + v[1]*v[1] + v[2]*v[2] + v[3]*v[3];
#pragma unroll
    for (int o = 32; o; o >>= 1) { s += __shfl_down(s, o); ss += __shfl_down(ss, o); }
    __shared__ float red[10];
    int w = tid >> 6;
    if ((tid & 63) == 0) { red[w] = s; red[4 + w] = ss; }
    __syncthreads();
    if (tid == 0) {
        float S = red[0] + red[1] + red[2] + red[3];
        float SS = red[4] + red[5] + red[6] + red[7];
        float mean = S * (1.f / 1024.f);
        float var  = SS * (1.f / 1024.f) - mean * mean;
        red[8] = mean; red[9] = rsqrtf(var + 1e-5f);
    }
    __syncthreads();
    float mean = red[8], rstd = red[9];
    USH* yr = y + (size_t)row * 1024 + tid * 4;
#pragma unroll
    for (int i = 0; i < 4; i++) {
        int c = tid * 4 + i;
        yr[i] = f2b((v[i] - mean) * rstd * g[c] + bb[c]);
    }
}

// =====================================================================
// zh = z @ wca + bca   (4096 rows, K=64, N=256)
// Emits bf16 coords zh_b[row][256] and per-head sumsq of the bf16-rounded
// coords: zsq[h][row]  (16 x 4096 f32).
// =====================================================================
__global__ __launch_bounds__(256) void zh_kernel(const float* __restrict__ z,
                                                 const float* __restrict__ wca,
                                                 const float* __restrict__ bca,
                                                 USH* __restrict__ zh_b,
                                                 float* __restrict__ zsq) {
    int row = blockIdx.x, n = threadIdx.x;
    __shared__ float zrow[64];
    if (n < 64) zrow[n] = z[(size_t)row * 64 + n];
    __syncthreads();
    float s = bca[n];
#pragma unroll 8
    for (int k = 0; k < 64; k++) s = fmaf(zrow[k], wca[(size_t)k * 256 + n], s);
    USH u = f2b(s);
    zh_b[(size_t)row * 256 + n] = u;
    float sv = b2f(u);
    float sq = sv * sv;
    sq += __shfl_xor(sq, 1); sq += __shfl_xor(sq, 2);
    sq += __shfl_xor(sq, 4); sq += __shfl_xor(sq, 8);
    if ((n & 15) == 0) zsq[(size_t)(n >> 4) * 4096 + row] = sq;
}

// =====================================================================
// z_next = hn(bf16 ws) @ wcn(f32) + bcn  (4096 rows, K=1024, N=64) -> f32
// =====================================================================
__global__ __launch_bounds__(256) void znext_kernel(const USH* __restrict__ hn,
                                                    const float* __restrict__ wcn,
                                                    const float* __restrict__ bcn,
                                                    float* __restrict__ zn) {
    int row = blockIdx.x, t = threadIdx.x;
    int n = t & 63, ks = t >> 6;
    const USH* a = hn + (size_t)row * 1024 + ks * 256;
    const float* w = wcn + (size_t)ks * 256 * 64 + n;
    float s = 0.f;
#pragma unroll 4
    for (int k = 0; k < 256; k++) s = fmaf(b2f(a[k]), w[(size_t)k * 64], s);
    __shared__ float part[4][64];
    part[ks][n] = s;
    __syncthreads();
    if (t < 64)
        zn[(size_t)row * 64 + t] = part[0][t] + part[1][t] + part[2][t] + part[3][t] + bcn[t];
}

// =====================================================================
// MFMA GEMM: C[M,N] = A[M,K](bf16) @ WT[N][K](bf16) + bias(f32)
// Tile BM x 128, BM = MI*32. 4 waves, BK=32.
// EPI: 0 = plain | 1 = +res | 2 = gelu | 3 = +res
// =====================================================================
template <int EPI, int MI, typename TRES, typename TOUT>
__global__ __launch_bounds__(256) void gemm_kernel(const USH* __restrict__ A,
                                                   const USH* __restrict__ WT,
                                                   const float* __restrict__ bias,
                                                   const TRES* __restrict__ res,
                                                   TOUT* __restrict__ out,
                                                   int M, int N, int K) {
    constexpr int BM = MI * 32;
    __shared__ __align__(16) USH lA[BM][40];   // [m][k], pad 32->40
    __shared__ __align__(16) USH lB[128][40];  // [n][k]
    int tid = threadIdx.x;
    int lane = tid & 63, wave = tid >> 6;
    int wr = wave >> 1, wc = wave & 1;
    int quad = lane >> 4, l15 = lane & 15;
    int m0 = blockIdx.y * BM, n0 = blockIdx.x * 128;

    int s_row = tid >> 2, s_k = (tid & 3) * 8;

    floatx4 acc[MI][4] = {};

    for (int k0 = 0; k0 < K; k0 += 32) {
#pragma unroll
        for (int r = 0; r < BM / 64; r++) {
            int row = s_row + r * 64;
            *(int4*)&lA[row][s_k] = *(const int4*)(A + (size_t)(m0 + row) * K + k0 + s_k);
        }
#pragma unroll
        for (int r = 0; r < 2; r++) {
            int row = s_row + r * 64;
            *(int4*)&lB[row][s_k] = *(const int4*)(WT + (size_t)(n0 + row) * K + k0 + s_k);
        }
        __syncthreads();
        bf16x8 bfr[4];
#pragma unroll
        for (int ni = 0; ni < 4; ni++)
            bfr[ni] = *(const bf16x8*)&lB[wc * 64 + ni * 16 + l15][quad * 8];
#pragma unroll
        for (int mi = 0; mi < MI; mi++) {
            bf16x8 afr = *(const bf16x8*)&lA[wr * (MI * 16) + mi * 16 + l15][quad * 8];
#pragma unroll
            for (int ni = 0; ni < 4; ni++)
                acc[mi][ni] = __builtin_amdgcn_mfma_f32_16x16x32_bf16(afr, bfr[ni], acc[mi][ni], 0, 0, 0);
        }
        __syncthreads();
    }

    float bias_v[4];
#pragma unroll
    for (int ni = 0; ni < 4; ni++) bias_v[ni] = bias[n0 + wc * 64 + ni * 16 + l15];

#pragma unroll
    for (int mi = 0; mi < MI; mi++) {
#pragma unroll
        for (int r = 0; r < 4; r++) {
            int row = m0 + wr * (MI * 16) + mi * 16 + quad * 4 + r;
            size_t base = (size_t)row * N;
#pragma unroll
            for (int ni = 0; ni < 4; ni++) {
                int col = n0 + wc * 64 + ni * 16 + l15;
                float v = acc[mi][ni][r] + bias_v[ni];
                if (EPI == 2) v = 0.5f * v * (1.f + erff(v * 0.70710678118f));
                if (EPI == 1 || EPI == 3) v += ldf(res + base + col);
                stf(out + base + col, v);
            }
        }
    }
}

// =====================================================================
// Flash distance-attention, MFMA, fixed-max softmax.
// Scores sc = -softplus(g)*max(|q|^2+|k|^2-2qk, 0) are <= 0 with the
// diagonal exactly 0 -> use m = 0 (softmax shift-invariant): no running
// max, no rescaling; l is lane-local, reduced once at the end.
// Coords pre-rounded to bf16 (zh_b) with per-head sumsq (zsq) from
// zh_kernel -> staging is pure copy.
// grid = (B*H = 32, S/64 = 32), block 256 (4 waves, 16 q-rows each).
// =====================================================================
__global__ __launch_bounds__(256) void attn3_kernel(const USH* __restrict__ zh_b,
                                                    const float* __restrict__ zsq,
                                                    const USH* __restrict__ value,
                                                    const float* __restrict__ gamma,
                                                    USH* __restrict__ attn_out) {
    int b = blockIdx.x >> 4, h = blockIdx.x & 15;
    int q0 = blockIdx.y * 64;
    int tid = threadIdx.x, lane = tid & 63, wq = tid >> 6;
    int quad = lane >> 4, l15 = lane & 15;

    __shared__ __align__(16) USH Qb[64][40];    // [q][coord 0..32), pads zero
    __shared__ __align__(16) USH KbT[64][40];   // [k][coord 0..32), pads zero
    __shared__ __align__(16) USH VbT[64][72];   // [dh][key]
    __shared__ __align__(16) USH Pb[4][16][72]; // per-wave P [q][key]
    __shared__ float Qs[64], Ks[64];

    // zero pad region [16,32) once
    for (int i = tid; i < 64 * 16; i += 256) {
        Qb[i >> 4][16 + (i & 15)] = 0;
        KbT[i >> 4][16 + (i & 15)] = 0;
    }

    const size_t zrow0 = (size_t)b * 2048;
    const float* zs = zsq + (size_t)h * 4096 + zrow0;
    const size_t vbase = zrow0 * 1024 + h * 64;

    {   // stage Q (bf16 copy)
        int q = tid >> 2, c0 = (tid & 3) * 4;
        *(uint2*)&Qb[q][c0] =
            *(const uint2*)(zh_b + (zrow0 + q0 + q) * 256 + h * 16 + c0);
    }
    if (tid < 64) Qs[tid] = zs[q0 + tid];
    __syncthreads();

    bf16x8 afragQ = *(const bf16x8*)&Qb[wq * 16 + l15][quad * 8];
    float qsr[4];
#pragma unroll
    for (int r = 0; r < 4; r++) qsr[r] = Qs[wq * 16 + quad * 4 + r];
    float gv; { float gx = gamma[h]; gv = log1pf(__expf(gx)); }

    floatx4 oacc[4] = {};
    float lr[4] = {0.f, 0.f, 0.f, 0.f};

    for (int kt = 0; kt < 2048; kt += 64) {
        __syncthreads();
        {   // stage K (bf16 copy)
            int k = tid >> 2, c0 = (tid & 3) * 4;
            *(uint2*)&KbT[k][c0] =
                *(const uint2*)(zh_b + (zrow0 + kt + k) * 256 + h * 16 + c0);
        }
        if (tid < 64) Ks[tid] = zs[kt + tid];
        {   // stage V transposed: 2 keys x 8 dh per thread, paired b32
            // writes -> dword addr (dh)*36 + (tid&31): conflict-free.
            int key2 = (tid & 31) * 2;
            int dh0 = (tid >> 5) * 8;
            const USH* s0 = value + vbase + (size_t)(kt + key2) * 1024 + dh0;
            int4 ta = *(const int4*)s0;
            int4 tb = *(const int4*)(s0 + 1024);
            const USH* ua = (const USH*)&ta;
            const USH* ub = (const USH*)&tb;
#pragma unroll
            for (int e = 0; e < 8; e++) {
                unsigned int dw = (unsigned int)ua[e] | ((unsigned int)ub[e] << 16);
                *(unsigned int*)&VbT[dh0 + e][key2] = dw;
            }
        }
        __syncthreads();

        // ---- QK^T ----
        floatx4 sacc[4];
#pragma unroll
        for (int ni = 0; ni < 4; ni++) {
            bf16x8 bk = *(const bf16x8*)&KbT[ni * 16 + l15][quad * 8];
            floatx4 z = {};
            sacc[ni] = __builtin_amdgcn_mfma_f32_16x16x32_bf16(afragQ, bk, z, 0, 0, 0);
        }
        float ksv[4];
#pragma unroll
        for (int ni = 0; ni < 4; ni++) ksv[ni] = Ks[ni * 16 + l15];

        // ---- p = exp(-g*d), m == 0 fixed; store truncated bf16 ----
#pragma unroll
        for (int r = 0; r < 4; r++) {
#pragma unroll
            for (int ni = 0; ni < 4; ni++) {
                float d = fmaxf(qsr[r] + ksv[ni] - 2.f * sacc[ni][r], 0.f);
                float pf = __expf(-gv * d);
                union { float f; unsigned int i; } cv; cv.f = pf;
                USH pt = (USH)(cv.i >> 16);
                Pb[wq][quad * 4 + r][ni * 16 + l15] = pt;
                lr[r] += b2f(pt);
            }
        }

        // ---- PV (Pb wave-private; same-wave LDS in-order) ----
#pragma unroll
        for (int ks2 = 0; ks2 < 2; ks2++) {
            bf16x8 ap = *(const bf16x8*)&Pb[wq][l15][ks2 * 32 + quad * 8];
#pragma unroll
            for (int nd = 0; nd < 4; nd++) {
                bf16x8 bv = *(const bf16x8*)&VbT[nd * 16 + l15][ks2 * 32 + quad * 8];
                oacc[nd] = __builtin_amdgcn_mfma_f32_16x16x32_bf16(ap, bv, oacc[nd], 0, 0, 0);
            }
        }
    }

    // ---- epilogue: reduce l across the 16-lane row group, store ----
#pragma unroll
    for (int r = 0; r < 4; r++) {
        float s = lr[r];
        s += __shfl_xor(s, 1); s += __shfl_xor(s, 2);
        s += __shfl_xor(s, 4); s += __shfl_xor(s, 8);
        float inv = 1.f / s;
        int row = q0 + wq * 16 + quad * 4 + r;
        USH* o = attn_out + (zrow0 + row) * 1024 + h * 64;
#pragma unroll
        for (int nd = 0; nd < 4; nd++) o[nd * 16 + l15] = f2b(oacc[nd][r] * inv);
    }
}

// =====================================================================
// z_out = LN(z + z_next) over rows of 64. block = 64 (one wave) per row.
// =====================================================================
__global__ __launch_bounds__(64) void lnc_kernel(const float* __restrict__ z,
                                                 const float* __restrict__ zn,
                                                 const float* __restrict__ g,
                                                 const float* __restrict__ bb,
                                                 float* __restrict__ out) {
    int row = blockIdx.x, t = threadIdx.x;
    float v = z[(size_t)row * 64 + t] + zn[(size_t)row * 64 + t];
    float s = v, ss = v * v;
#pragma unroll
    for (int o = 32; o; o >>= 1) { s += __shfl_xor(s, o); ss += __shfl_xor(ss, o); }
    float mean = s * (1.f / 64.f);
    float rstd = rsqrtf(ss * (1.f / 64.f) - mean * mean + 1e-5f);
    out[(size_t)row * 64 + t] = (v - mean) * rstd * g[t] + bb[t];
}

// =====================================================================
extern "C" void kernel_launch(void* const* d_in, const int* in_sizes, int n_in,
                              void* d_out, int out_size, void* d_ws, size_t ws_size,
                              hipStream_t stream) {
    // workspace layout (61 MB):
    //   [0,8M)       value (bf16)    -- dead after attn
    //   [8,16M)      attn_o (bf16)   -- dead after wo-gemm
    //   [16,18M)     zh_b (bf16 [4096][256])   -- dead after attn
    //   [18,18.25M)  zsq (f32 [16][4096])      -- dead after attn
    //   [20,28M)     hn (bf16)       -- dead after znext
    //   [0,32M)      mid (bf16)      -- overlays the above (written step 8)
    //   [32,40M)     hn2 (bf16)
    //   [40,41M)     znext (f32)
    //   [41,43M)     wvT   [43,45M) woT   [45,53M) w1T   [53,61M) w2T
    // h1 (f32) lives in d_out's h region.
    char* p = (char*)d_ws;
    USH*   value  = (USH*)(p);
    USH*   attn_o = (USH*)(p + ((size_t)8  << 20));
    USH*   zh_b   = (USH*)(p + ((size_t)16 << 20));
    float* zsq    = (float*)(p + ((size_t)18 << 20));
    USH*   hn     = (USH*)(p + ((size_t)20 << 20));
    USH*   mid    = (USH*)(p);
    USH*   hn2    = (USH*)(p + ((size_t)32 << 20));
    float* znext  = (float*)(p + ((size_t)40 << 20));
    USH*   wvT    = (USH*)(p + ((size_t)41 << 20));
    USH*   woT    = (USH*)(p + ((size_t)43 << 20));
    USH*   w1T    = (USH*)(p + ((size_t)45 << 20));
    USH*   w2T    = (USH*)(p + ((size_t)53 << 20));

    const float *h    = (const float*)d_in[0],  *z    = (const float*)d_in[1];
    const float *wv   = (const float*)d_in[2],  *bv   = (const float*)d_in[3];
    const float *wca  = (const float*)d_in[4],  *bca  = (const float*)d_in[5];
    const float *wcn  = (const float*)d_in[6],  *bcn  = (const float*)d_in[7];
    const float *wo   = (const float*)d_in[8],  *bo   = (const float*)d_in[9];
    const float *gam  = (const float*)d_in[10];
    const float *w1   = (const float*)d_in[11], *b1   = (const float*)d_in[12];
    const float *w2   = (const float*)d_in[13], *b2   = (const float*)d_in[14];
    const float *ln1g = (const float*)d_in[15], *ln1b = (const float*)d_in[16];
    const float *ln2g = (const float*)d_in[17], *ln2b = (const float*)d_in[18];
    const float *lncg = (const float*)d_in[19], *lncb = (const float*)d_in[20];

    float* out_h = (float*)d_out;
    float* out_z = out_h + (size_t)4096 * 1024;
    float* h1    = out_h;

    // 0. weight conversion (f32 [K][N] -> bf16 [N][K])
    transpose_f2b<<<dim3(16, 16), 256, 0, stream>>>(wv, wvT, 1024, 1024);
    transpose_f2b<<<dim3(16, 16), 256, 0, stream>>>(wo, woT, 1024, 1024);
    transpose_f2b<<<dim3(64, 16), 256, 0, stream>>>(w1, w1T, 1024, 4096);
    transpose_f2b<<<dim3(16, 64), 256, 0, stream>>>(w2, w2T, 4096, 1024);

    // 1. hn = LN1(h)
    ln_rows<float><<<4096, 256, 0, stream>>>(h, ln1g, ln1b, hn);
    // 2. zh_b, zsq = coords(z)
    zh_kernel<<<4096, 256, 0, stream>>>(z, wca, bca, zh_b, zsq);
    // 3. value = hn @ wv + bv
    gemm_kernel<0, 2, USH, USH><<<dim3(8, 64), 256, 0, stream>>>(hn, wvT, bv, (const USH*)nullptr, value, 4096, 1024, 1024);
    // 4. z_next = hn @ wcn + bcn
    znext_kernel<<<4096, 256, 0, stream>>>(hn, wcn, bcn, znext);
    // 5. attention (MFMA flash, fixed-max)
    attn3_kernel<<<dim3(32, 32), 256, 0, stream>>>(zh_b, zsq, value, gam, attn_o);
    // 6. h1 = h + attn_o @ wo + bo     (out f32 -> d_out h-region)
    gemm_kernel<1, 2, float, float><<<dim3(8, 64), 256, 0, stream>>>(attn_o, woT, bo, h, h1, 4096, 1024, 1024);
    // 7. hn2 = LN2(h1)
    ln_rows<float><<<4096, 256, 0, stream>>>(h1, ln2g, ln2b, hn2);
    // 8. mid = gelu(hn2 @ w1 + b1)
    gemm_kernel<2, 4, USH, USH><<<dim3(32, 32), 256, 0, stream>>>(hn2, w1T, b1, (const USH*)nullptr, mid, 4096, 4096, 1024);
    // 9. out_h = h1 + mid @ w2 + b2    (res==out same-thread, safe)
    gemm_kernel<3, 2, float, float><<<dim3(8, 64), 256, 0, stream>>>(mid, w2T, b2, h1, out_h, 4096, 1024, 4096);
    // 10. out_z = LN(z + znext)
    lnc_kernel<<<4096, 64, 0, stream>>>(z, znext, lncg, lncb, out_z);
}

// Round 7
// 484.933 us; speedup vs baseline: 3.1930x; 1.0231x over previous
//
#include <hip/hip_runtime.h>

#define USH unsigned short

// ---------- bf16 helpers (storage = unsigned short) ----------
__device__ __forceinline__ float b2f(USH u) {
    union { unsigned int i; float f; } x; x.i = ((unsigned int)u) << 16; return x.f;
}
__device__ __forceinline__ USH f2b(float f) {
    union { float f; unsigned int i; } x; x.f = f;
    unsigned int r = x.i + (0x7fffu + ((x.i >> 16) & 1u));  // RNE
    return (USH)(r >> 16);
}
__device__ __forceinline__ float ldf(const USH* p)  { return b2f(*p); }
__device__ __forceinline__ float ldf(const float* p){ return *p; }
__device__ __forceinline__ void stf(USH* p, float v)  { *p = f2b(v); }
__device__ __forceinline__ void stf(float* p, float v){ *p = v; }

// async global->LDS, 16B per lane (dest = wave-uniform base + lane*16)
#define GLOAD16(gp, lp) __builtin_amdgcn_global_load_lds(                     \
    (const __attribute__((address_space(1))) void*)(gp),                      \
    (__attribute__((address_space(3))) void*)(lp), 16, 0, 0)

typedef __attribute__((ext_vector_type(8))) __bf16 bf16x8;
typedef __attribute__((ext_vector_type(4))) float  floatx4;

// =====================================================================
// Weight transpose+convert: W[K][N] f32 -> WT[N][K] bf16.
// 64x64 tiles, grid (N/64, K/64), block 256.
// =====================================================================
__global__ __launch_bounds__(256) void transpose_f2b(const float* __restrict__ W,
                                                     USH* __restrict__ WT,
                                                     int K, int N) {
    __shared__ USH t[64][72];
    int n0 = blockIdx.x * 64, k0 = blockIdx.y * 64;
    int tid = threadIdx.x;
    int kr = tid >> 4, nc = (tid & 15) * 4;
#pragma unroll
    for (int r = 0; r < 4; r++) {
        int k = kr + r * 16;
        float4 v = *(const float4*)(W + (size_t)(k0 + k) * N + n0 + nc);
        t[nc + 0][k] = f2b(v.x); t[nc + 1][k] = f2b(v.y);
        t[nc + 2][k] = f2b(v.z); t[nc + 3][k] = f2b(v.w);
    }
    __syncthreads();
    int nr = tid >> 2, kc = (tid & 3) * 8;
#pragma unroll
    for (int r = 0; r < 2; r++) {
        int k = kc + r * 32;
        *(int4*)(WT + (size_t)(n0 + nr) * K + k0 + k) = *(const int4*)&t[nr][k];
    }
}

// =====================================================================
// LayerNorm rows of 1024. block=256, one block/row.
// =====================================================================
template <typename TX>
__global__ __launch_bounds__(256) void ln_rows(const TX* __restrict__ x,
                                               const float* __restrict__ g,
                                               const float* __restrict__ bb,
                                               USH* __restrict__ y) {
    int row = blockIdx.x, tid = threadIdx.x;
    const TX* xr = x + (size_t)row * 1024 + tid * 4;
    float v[4];
#pragma unroll
    for (int i = 0; i < 4; i++) v[i] = ldf(xr + i);
    float s  = v[0] + v[1] + v[2] + v[3];
    float ss = v[0]*v[0] + v[1]*v[1] + v[2]*v[2] + v[3]*v[3];
#pragma unroll
    for (int o = 32; o; o >>= 1) { s += __shfl_down(s, o); ss += __shfl_down(ss, o); }
    __shared__ float red[10];
    int w = tid >> 6;
    if ((tid & 63) == 0) { red[w] = s; red[4 + w] = ss; }
    __syncthreads();
    if (tid == 0) {
        float S = red[0] + red[1] + red[2] + red[3];
        float SS = red[4] + red[5] + red[6] + red[7];
        float mean = S * (1.f / 1024.f);
        float var  = SS * (1.f / 1024.f) - mean * mean;
        red[8] = mean; red[9] = rsqrtf(var + 1e-5f);
    }
    __syncthreads();
    float mean = red[8], rstd = red[9];
    USH* yr = y + (size_t)row * 1024 + tid * 4;
#pragma unroll
    for (int i = 0; i < 4; i++) {
        int c = tid * 4 + i;
        yr[i] = f2b((v[i] - mean) * rstd * g[c] + bb[c]);
    }
}

// =====================================================================
// zh = z @ wca + bca   (4096 rows, K=64, N=256)
// Emits bf16 coords zh_b and per-head sumsq zsq[h][row].
// =====================================================================
__global__ __launch_bounds__(256) void zh_kernel(const float* __restrict__ z,
                                                 const float* __restrict__ wca,
                                                 const float* __restrict__ bca,
                                                 USH* __restrict__ zh_b,
                                                 float* __restrict__ zsq) {
    int row = blockIdx.x, n = threadIdx.x;
    __shared__ float zrow[64];
    if (n < 64) zrow[n] = z[(size_t)row * 64 + n];
    __syncthreads();
    float s = bca[n];
#pragma unroll 8
    for (int k = 0; k < 64; k++) s = fmaf(zrow[k], wca[(size_t)k * 256 + n], s);
    USH u = f2b(s);
    zh_b[(size_t)row * 256 + n] = u;
    float sv = b2f(u);
    float sq = sv * sv;
    sq += __shfl_xor(sq, 1); sq += __shfl_xor(sq, 2);
    sq += __shfl_xor(sq, 4); sq += __shfl_xor(sq, 8);
    if ((n & 15) == 0) zsq[(size_t)(n >> 4) * 4096 + row] = sq;
}

// =====================================================================
// z_next = hn(bf16 ws) @ wcn(f32) + bcn  (4096 rows, K=1024, N=64) -> f32
// =====================================================================
__global__ __launch_bounds__(256) void znext_kernel(const USH* __restrict__ hn,
                                                    const float* __restrict__ wcn,
                                                    const float* __restrict__ bcn,
                                                    float* __restrict__ zn) {
    int row = blockIdx.x, t = threadIdx.x;
    int n = t & 63, ks = t >> 6;
    const USH* a = hn + (size_t)row * 1024 + ks * 256;
    const float* w = wcn + (size_t)ks * 256 * 64 + n;
    float s = 0.f;
#pragma unroll 4
    for (int k = 0; k < 256; k++) s = fmaf(b2f(a[k]), w[(size_t)k * 64], s);
    __shared__ float part[4][64];
    part[ks][n] = s;
    __syncthreads();
    if (t < 64)
        zn[(size_t)row * 64 + t] = part[0][t] + part[1][t] + part[2][t] + part[3][t] + bcn[t];
}

// =====================================================================
// MFMA GEMM v2: C[M,N] = A[M,K](bf16) @ WT[N][K](bf16) + bias(f32)
// Tile BM x 128 (BM = MI*32), BK=32, 4 waves.
// Staging via global_load_lds (16B/lane, UNPADDED LDS tiles -- the
// wave-uniform-base+lane*16 contract requires contiguous lane order).
// Grid: blockIdx.x = m-block (fast) so the blocks sharing an A-stripe
// are congruent mod 8 -> same XCD -> A-stripe stays in that XCD's L2.
// EPI: 0 = plain | 1 = +res | 2 = gelu | 3 = +res
// =====================================================================
template <int EPI, int MI, typename TRES, typename TOUT>
__global__ __launch_bounds__(256) void gemm_kernel(const USH* __restrict__ A,
                                                   const USH* __restrict__ WT,
                                                   const float* __restrict__ bias,
                                                   const TRES* __restrict__ res,
                                                   TOUT* __restrict__ out,
                                                   int M, int N, int K) {
    constexpr int BM = MI * 32;
    __shared__ __align__(16) USH lA[BM][32];   // unpadded: global_load_lds dest
    __shared__ __align__(16) USH lB[128][32];
    int tid = threadIdx.x;
    int lane = tid & 63, wave = tid >> 6;
    int wr = wave >> 1, wc = wave & 1;
    int quad = lane >> 4, l15 = lane & 15;
    int m0 = blockIdx.x * BM, n0 = blockIdx.y * 128;

    int s_row = tid >> 2, s_k = (tid & 3) * 8;

    const USH* gA = A + (size_t)(m0 + s_row) * K + s_k;
    const USH* gB = WT + (size_t)(n0 + s_row) * K + s_k;
    USH* lA0 = &lA[0][0] + tid * 8;            // tid*16 bytes
    USH* lB0 = &lB[0][0] + tid * 8;

    floatx4 acc[MI][4] = {};

    for (int k0 = 0; k0 < K; k0 += 32) {
#pragma unroll
        for (int r = 0; r < BM / 64; r++)
            GLOAD16(gA + (size_t)r * 64 * K + k0, lA0 + r * 2048);
#pragma unroll
        for (int r = 0; r < 2; r++)
            GLOAD16(gB + (size_t)r * 64 * K + k0, lB0 + r * 2048);
        __syncthreads();   // drains vmcnt(0) before barrier

        bf16x8 bfr[4];
#pragma unroll
        for (int ni = 0; ni < 4; ni++)
            bfr[ni] = *(const bf16x8*)&lB[wc * 64 + ni * 16 + l15][quad * 8];
#pragma unroll
        for (int mi = 0; mi < MI; mi++) {
            bf16x8 afr = *(const bf16x8*)&lA[wr * (MI * 16) + mi * 16 + l15][quad * 8];
#pragma unroll
            for (int ni = 0; ni < 4; ni++)
                acc[mi][ni] = __builtin_amdgcn_mfma_f32_16x16x32_bf16(afr, bfr[ni], acc[mi][ni], 0, 0, 0);
        }
        __syncthreads();
    }

    float bias_v[4];
#pragma unroll
    for (int ni = 0; ni < 4; ni++) bias_v[ni] = bias[n0 + wc * 64 + ni * 16 + l15];

#pragma unroll
    for (int mi = 0; mi < MI; mi++) {
#pragma unroll
        for (int r = 0; r < 4; r++) {
            int row = m0 + wr * (MI * 16) + mi * 16 + quad * 4 + r;
            size_t base = (size_t)row * N;
#pragma unroll
            for (int ni = 0; ni < 4; ni++) {
                int col = n0 + wc * 64 + ni * 16 + l15;
                float v = acc[mi][ni][r] + bias_v[ni];
                if (EPI == 2) v = 0.5f * v * (1.f + erff(v * 0.70710678118f));
                if (EPI == 1 || EPI == 3) v += ldf(res + base + col);
                stf(out + base + col, v);
            }
        }
    }
}

// =====================================================================
// Flash distance-attention, MFMA, fixed-max softmax (R6-validated).
// =====================================================================
__global__ __launch_bounds__(256) void attn3_kernel(const USH* __restrict__ zh_b,
                                                    const float* __restrict__ zsq,
                                                    const USH* __restrict__ value,
                                                    const float* __restrict__ gamma,
                                                    USH* __restrict__ attn_out) {
    int b = blockIdx.x >> 4, h = blockIdx.x & 15;
    int q0 = blockIdx.y * 64;
    int tid = threadIdx.x, lane = tid & 63, wq = tid >> 6;
    int quad = lane >> 4, l15 = lane & 15;

    __shared__ __align__(16) USH Qb[64][40];
    __shared__ __align__(16) USH KbT[64][40];
    __shared__ __align__(16) USH VbT[64][72];
    __shared__ __align__(16) USH Pb[4][16][72];
    __shared__ float Qs[64], Ks[64];

    for (int i = tid; i < 64 * 16; i += 256) {
        Qb[i >> 4][16 + (i & 15)] = 0;
        KbT[i >> 4][16 + (i & 15)] = 0;
    }

    const size_t zrow0 = (size_t)b * 2048;
    const float* zs = zsq + (size_t)h * 4096 + zrow0;
    const size_t vbase = zrow0 * 1024 + h * 64;

    {
        int q = tid >> 2, c0 = (tid & 3) * 4;
        *(uint2*)&Qb[q][c0] =
            *(const uint2*)(zh_b + (zrow0 + q0 + q) * 256 + h * 16 + c0);
    }
    if (tid < 64) Qs[tid] = zs[q0 + tid];
    __syncthreads();

    bf16x8 afragQ = *(const bf16x8*)&Qb[wq * 16 + l15][quad * 8];
    float qsr[4];
#pragma unroll
    for (int r = 0; r < 4; r++) qsr[r] = Qs[wq * 16 + quad * 4 + r];
    float gv; { float gx = gamma[h]; gv = log1pf(__expf(gx)); }

    floatx4 oacc[4] = {};
    float lr[4] = {0.f, 0.f, 0.f, 0.f};

    for (int kt = 0; kt < 2048; kt += 64) {
        __syncthreads();
        {
            int k = tid >> 2, c0 = (tid & 3) * 4;
            *(uint2*)&KbT[k][c0] =
                *(const uint2*)(zh_b + (zrow0 + kt + k) * 256 + h * 16 + c0);
        }
        if (tid < 64) Ks[tid] = zs[kt + tid];
        {
            int key2 = (tid & 31) * 2;
            int dh0 = (tid >> 5) * 8;
            const USH* s0 = value + vbase + (size_t)(kt + key2) * 1024 + dh0;
            int4 ta = *(const int4*)s0;
            int4 tb = *(const int4*)(s0 + 1024);
            const USH* ua = (const USH*)&ta;
            const USH* ub = (const USH*)&tb;
#pragma unroll
            for (int e = 0; e < 8; e++) {
                unsigned int dw = (unsigned int)ua[e] | ((unsigned int)ub[e] << 16);
                *(unsigned int*)&VbT[dh0 + e][key2] = dw;
            }
        }
        __syncthreads();

        floatx4 sacc[4];
#pragma unroll
        for (int ni = 0; ni < 4; ni++) {
            bf16x8 bk = *(const bf16x8*)&KbT[ni * 16 + l15][quad * 8];
            floatx4 z = {};
            sacc[ni] = __builtin_amdgcn_mfma_f32_16x16x32_bf16(afragQ, bk, z, 0, 0, 0);
        }
        float ksv[4];
#pragma unroll
        for (int ni = 0; ni < 4; ni++) ksv[ni] = Ks[ni * 16 + l15];

#pragma unroll
        for (int r = 0; r < 4; r++) {
#pragma unroll
            for (int ni = 0; ni < 4; ni++) {
                float d = fmaxf(qsr[r] + ksv[ni] - 2.f * sacc[ni][r], 0.f);
                float pf = __expf(-gv * d);
                union { float f; unsigned int i; } cv; cv.f = pf;
                USH pt = (USH)(cv.i >> 16);
                Pb[wq][quad * 4 + r][ni * 16 + l15] = pt;
                lr[r] += b2f(pt);
            }
        }

#pragma unroll
        for (int ks2 = 0; ks2 < 2; ks2++) {
            bf16x8 ap = *(const bf16x8*)&Pb[wq][l15][ks2 * 32 + quad * 8];
#pragma unroll
            for (int nd = 0; nd < 4; nd++) {
                bf16x8 bv = *(const bf16x8*)&VbT[nd * 16 + l15][ks2 * 32 + quad * 8];
                oacc[nd] = __builtin_amdgcn_mfma_f32_16x16x32_bf16(ap, bv, oacc[nd], 0, 0, 0);
            }
        }
    }

#pragma unroll
    for (int r = 0; r < 4; r++) {
        float s = lr[r];
        s += __shfl_xor(s, 1); s += __shfl_xor(s, 2);
        s += __shfl_xor(s, 4); s += __shfl_xor(s, 8);
        float inv = 1.f / s;
        int row = q0 + wq * 16 + quad * 4 + r;
        USH* o = attn_out + (zrow0 + row) * 1024 + h * 64;
#pragma unroll
        for (int nd = 0; nd < 4; nd++) o[nd * 16 + l15] = f2b(oacc[nd][r] * inv);
    }
}

// =====================================================================
// z_out = LN(z + z_next) over rows of 64. block = 64 (one wave) per row.
// =====================================================================
__global__ __launch_bounds__(64) void lnc_kernel(const float* __restrict__ z,
                                                 const float* __restrict__ zn,
                                                 const float* __restrict__ g,
                                                 const float* __restrict__ bb,
                                                 float* __restrict__ out) {
    int row = blockIdx.x, t = threadIdx.x;
    float v = z[(size_t)row * 64 + t] + zn[(size_t)row * 64 + t];
    float s = v, ss = v * v;
#pragma unroll
    for (int o = 32; o; o >>= 1) { s += __shfl_xor(s, o); ss += __shfl_xor(ss, o); }
    float mean = s * (1.f / 64.f);
    float rstd = rsqrtf(ss * (1.f / 64.f) - mean * mean + 1e-5f);
    out[(size_t)row * 64 + t] = (v - mean) * rstd * g[t] + bb[t];
}

// =====================================================================
extern "C" void kernel_launch(void* const* d_in, const int* in_sizes, int n_in,
                              void* d_out, int out_size, void* d_ws, size_t ws_size,
                              hipStream_t stream) {
    // workspace layout (61 MB):
    //   [0,8M)       value (bf16)    -- dead after attn
    //   [8,16M)      attn_o (bf16)   -- dead after wo-gemm
    //   [16,18M)     zh_b (bf16)     -- dead after attn
    //   [18,18.25M)  zsq (f32)       -- dead after attn
    //   [20,28M)     hn (bf16)       -- dead after znext
    //   [0,32M)      mid (bf16)      -- overlays the above (written step 8)
    //   [32,40M)     hn2 (bf16)
    //   [40,41M)     znext (f32)
    //   [41,43M)     wvT   [43,45M) woT   [45,53M) w1T   [53,61M) w2T
    // h1 (f32) lives in d_out's h region.
    char* p = (char*)d_ws;
    USH*   value  = (USH*)(p);
    USH*   attn_o = (USH*)(p + ((size_t)8  << 20));
    USH*   zh_b   = (USH*)(p + ((size_t)16 << 20));
    float* zsq    = (float*)(p + ((size_t)18 << 20));
    USH*   hn     = (USH*)(p + ((size_t)20 << 20));
    USH*   mid    = (USH*)(p);
    USH*   hn2    = (USH*)(p + ((size_t)32 << 20));
    float* znext  = (float*)(p + ((size_t)40 << 20));
    USH*   wvT    = (USH*)(p + ((size_t)41 << 20));
    USH*   woT    = (USH*)(p + ((size_t)43 << 20));
    USH*   w1T    = (USH*)(p + ((size_t)45 << 20));
    USH*   w2T    = (USH*)(p + ((size_t)53 << 20));

    const float *h    = (const float*)d_in[0],  *z    = (const float*)d_in[1];
    const float *wv   = (const float*)d_in[2],  *bv   = (const float*)d_in[3];
    const float *wca  = (const float*)d_in[4],  *bca  = (const float*)d_in[5];
    const float *wcn  = (const float*)d_in[6],  *bcn  = (const float*)d_in[7];
    const float *wo   = (const float*)d_in[8],  *bo   = (const float*)d_in[9];
    const float *gam  = (const float*)d_in[10];
    const float *w1   = (const float*)d_in[11], *b1   = (const float*)d_in[12];
    const float *w2   = (const float*)d_in[13], *b2   = (const float*)d_in[14];
    const float *ln1g = (const float*)d_in[15], *ln1b = (const float*)d_in[16];
    const float *ln2g = (const float*)d_in[17], *ln2b = (const float*)d_in[18];
    const float *lncg = (const float*)d_in[19], *lncb = (const float*)d_in[20];

    float* out_h = (float*)d_out;
    float* out_z = out_h + (size_t)4096 * 1024;
    float* h1    = out_h;

    // 0. weight conversion (f32 [K][N] -> bf16 [N][K])
    transpose_f2b<<<dim3(16, 16), 256, 0, stream>>>(wv, wvT, 1024, 1024);
    transpose_f2b<<<dim3(16, 16), 256, 0, stream>>>(wo, woT, 1024, 1024);
    transpose_f2b<<<dim3(64, 16), 256, 0, stream>>>(w1, w1T, 1024, 4096);
    transpose_f2b<<<dim3(16, 64), 256, 0, stream>>>(w2, w2T, 4096, 1024);

    // 1. hn = LN1(h)
    ln_rows<float><<<4096, 256, 0, stream>>>(h, ln1g, ln1b, hn);
    // 2. zh_b, zsq = coords(z)
    zh_kernel<<<4096, 256, 0, stream>>>(z, wca, bca, zh_b, zsq);
    // 3. value = hn @ wv + bv           (grid: m-blocks fast -> XCD affinity)
    gemm_kernel<0, 2, USH, USH><<<dim3(64, 8), 256, 0, stream>>>(hn, wvT, bv, (const USH*)nullptr, value, 4096, 1024, 1024);
    // 4. z_next = hn @ wcn + bcn
    znext_kernel<<<4096, 256, 0, stream>>>(hn, wcn, bcn, znext);
    // 5. attention (MFMA flash, fixed-max)
    attn3_kernel<<<dim3(32, 32), 256, 0, stream>>>(zh_b, zsq, value, gam, attn_o);
    // 6. h1 = h + attn_o @ wo + bo      (out f32 -> d_out h-region)
    gemm_kernel<1, 2, float, float><<<dim3(64, 8), 256, 0, stream>>>(attn_o, woT, bo, h, h1, 4096, 1024, 1024);
    // 7. hn2 = LN2(h1)
    ln_rows<float><<<4096, 256, 0, stream>>>(h1, ln2g, ln2b, hn2);
    // 8. mid = gelu(hn2 @ w1 + b1)
    gemm_kernel<2, 4, USH, USH><<<dim3(32, 32), 256, 0, stream>>>(hn2, w1T, b1, (const USH*)nullptr, mid, 4096, 4096, 1024);
    // 9. out_h = h1 + mid @ w2 + b2     (res==out same-thread, safe)
    gemm_kernel<3, 2, float, float><<<dim3(64, 8), 256, 0, stream>>>(mid, w2T, b2, h1, out_h, 4096, 1024, 4096);
    // 10. out_z = LN(z + znext)
    lnc_kernel<<<4096, 64, 0, stream>>>(z, znext, lncg, lncb, out_z);
}

// Round 8
// 472.664 us; speedup vs baseline: 3.2759x; 1.0260x over previous
//
#include <hip/hip_runtime.h>

#define USH unsigned short

// ---------- bf16 helpers (storage = unsigned short) ----------
__device__ __forceinline__ float b2f(USH u) {
    union { unsigned int i; float f; } x; x.i = ((unsigned int)u) << 16; return x.f;
}
__device__ __forceinline__ USH f2b(float f) {
    union { float f; unsigned int i; } x; x.f = f;
    unsigned int r = x.i + (0x7fffu + ((x.i >> 16) & 1u));  // RNE
    return (USH)(r >> 16);
}
__device__ __forceinline__ float ldf(const USH* p)  { return b2f(*p); }
__device__ __forceinline__ float ldf(const float* p){ return *p; }
__device__ __forceinline__ void stf(USH* p, float v)  { *p = f2b(v); }
__device__ __forceinline__ void stf(float* p, float v){ *p = v; }

// async global->LDS, 16B per lane (dest = wave-uniform base + lane*16)
#define GLOAD16(gp, lp) __builtin_amdgcn_global_load_lds(                     \
    (const __attribute__((address_space(1))) void*)(gp),                      \
    (__attribute__((address_space(3))) void*)(lp), 16, 0, 0)

typedef __attribute__((ext_vector_type(8))) __bf16 bf16x8;
typedef __attribute__((ext_vector_type(4))) float  floatx4;

// =====================================================================
// Weight transpose+convert: W[K][N] f32 -> WT[N][K] bf16.
// =====================================================================
__global__ __launch_bounds__(256) void transpose_f2b(const float* __restrict__ W,
                                                     USH* __restrict__ WT,
                                                     int K, int N) {
    __shared__ USH t[64][72];
    int n0 = blockIdx.x * 64, k0 = blockIdx.y * 64;
    int tid = threadIdx.x;
    int kr = tid >> 4, nc = (tid & 15) * 4;
#pragma unroll
    for (int r = 0; r < 4; r++) {
        int k = kr + r * 16;
        float4 v = *(const float4*)(W + (size_t)(k0 + k) * N + n0 + nc);
        t[nc + 0][k] = f2b(v.x); t[nc + 1][k] = f2b(v.y);
        t[nc + 2][k] = f2b(v.z); t[nc + 3][k] = f2b(v.w);
    }
    __syncthreads();
    int nr = tid >> 2, kc = (tid & 3) * 8;
#pragma unroll
    for (int r = 0; r < 2; r++) {
        int k = kc + r * 32;
        *(int4*)(WT + (size_t)(n0 + nr) * K + k0 + k) = *(const int4*)&t[nr][k];
    }
}

// =====================================================================
// LayerNorm rows of 1024. block=256, one block/row.
// =====================================================================
template <typename TX>
__global__ __launch_bounds__(256) void ln_rows(const TX* __restrict__ x,
                                               const float* __restrict__ g,
                                               const float* __restrict__ bb,
                                               USH* __restrict__ y) {
    int row = blockIdx.x, tid = threadIdx.x;
    const TX* xr = x + (size_t)row * 1024 + tid * 4;
    float v[4];
#pragma unroll
    for (int i = 0; i < 4; i++) v[i] = ldf(xr + i);
    float s  = v[0] + v[1] + v[2] + v[3];
    float ss = v[0]*v[0] + v[1]*v[1] + v[2]*v[2] + v[3]*v[3];
#pragma unroll
    for (int o = 32; o; o >>= 1) { s += __shfl_down(s, o); ss += __shfl_down(ss, o); }
    __shared__ float red[10];
    int w = tid >> 6;
    if ((tid & 63) == 0) { red[w] = s; red[4 + w] = ss; }
    __syncthreads();
    if (tid == 0) {
        float S = red[0] + red[1] + red[2] + red[3];
        float SS = red[4] + red[5] + red[6] + red[7];
        float mean = S * (1.f / 1024.f);
        float var  = SS * (1.f / 1024.f) - mean * mean;
        red[8] = mean; red[9] = rsqrtf(var + 1e-5f);
    }
    __syncthreads();
    float mean = red[8], rstd = red[9];
    USH* yr = y + (size_t)row * 1024 + tid * 4;
#pragma unroll
    for (int i = 0; i < 4; i++) {
        int c = tid * 4 + i;
        yr[i] = f2b((v[i] - mean) * rstd * g[c] + bb[c]);
    }
}

// =====================================================================
// zh = z @ wca + bca, emitting packed MFMA operand rows (head-major):
//  zq_pack[h][row][32]: [-2*gv*s (16)], [16]=gv*ks, [17]=gv, [18]=gv, 0..
//  zk_pack[h][row][32]: [ f2b(s) (16)], [16]=1.0,  [17]=ks_hi, [18]=ks_lo, 0..
// so that mfma(zq_row, zk_row) = gv * (qs + ks - 2 q.k) directly.
// qs uses same sumsq as ks; its bf16 error is per-q-row constant and
// cancels exactly in softmax normalization.
// =====================================================================
__global__ __launch_bounds__(256) void zh_kernel(const float* __restrict__ z,
                                                 const float* __restrict__ wca,
                                                 const float* __restrict__ bca,
                                                 const float* __restrict__ gamma,
                                                 USH* __restrict__ zq_pack,
                                                 USH* __restrict__ zk_pack) {
    int row = blockIdx.x, n = threadIdx.x;
    __shared__ float zrow[64];
    if (n < 64) zrow[n] = z[(size_t)row * 64 + n];
    __syncthreads();
    float s = bca[n];
#pragma unroll 8
    for (int k = 0; k < 64; k++) s = fmaf(zrow[k], wca[(size_t)k * 256 + n], s);
    int h = n >> 4, c = n & 15;
    float gv = log1pf(__expf(gamma[h]));   // softplus
    USH u = f2b(s);
    float sv = b2f(u);
    float sq = sv * sv;
    sq += __shfl_xor(sq, 1); sq += __shfl_xor(sq, 2);
    sq += __shfl_xor(sq, 4); sq += __shfl_xor(sq, 8);
    size_t base = ((size_t)h * 4096 + row) * 32;
    zk_pack[base + c] = u;
    zq_pack[base + c] = f2b(-2.f * gv * s);
    if (c == 0) {
        USH hi = f2b(sq);
        float lo = sq - b2f(hi);
        unsigned int kw0 = 0x3F80u | ((unsigned int)hi << 16);
        unsigned int kw1 = (unsigned int)f2b(lo);
        uint4 kv = {kw0, kw1, 0u, 0u};
        uint4 zz = {0u, 0u, 0u, 0u};
        *(uint4*)(zk_pack + base + 16) = kv;
        *(uint4*)(zk_pack + base + 24) = zz;
        unsigned int qw0 = (unsigned int)f2b(gv * sq) | ((unsigned int)f2b(gv) << 16);
        unsigned int qw1 = (unsigned int)f2b(gv);
        uint4 qv = {qw0, qw1, 0u, 0u};
        *(uint4*)(zq_pack + base + 16) = qv;
        *(uint4*)(zq_pack + base + 24) = zz;
    }
}

// =====================================================================
// z_next = hn(bf16 ws) @ wcn(f32) + bcn  (4096 rows, K=1024, N=64) -> f32
// =====================================================================
__global__ __launch_bounds__(256) void znext_kernel(const USH* __restrict__ hn,
                                                    const float* __restrict__ wcn,
                                                    const float* __restrict__ bcn,
                                                    float* __restrict__ zn) {
    int row = blockIdx.x, t = threadIdx.x;
    int n = t & 63, ks = t >> 6;
    const USH* a = hn + (size_t)row * 1024 + ks * 256;
    const float* w = wcn + (size_t)ks * 256 * 64 + n;
    float s = 0.f;
#pragma unroll 4
    for (int k = 0; k < 256; k++) s = fmaf(b2f(a[k]), w[(size_t)k * 64], s);
    __shared__ float part[4][64];
    part[ks][n] = s;
    __syncthreads();
    if (t < 64)
        zn[(size_t)row * 64 + t] = part[0][t] + part[1][t] + part[2][t] + part[3][t] + bcn[t];
}

// =====================================================================
// MFMA GEMM v2 (R7-validated): global_load_lds staging, XCD-affine grid.
// =====================================================================
template <int EPI, int MI, typename TRES, typename TOUT>
__global__ __launch_bounds__(256) void gemm_kernel(const USH* __restrict__ A,
                                                   const USH* __restrict__ WT,
                                                   const float* __restrict__ bias,
                                                   const TRES* __restrict__ res,
                                                   TOUT* __restrict__ out,
                                                   int M, int N, int K) {
    constexpr int BM = MI * 32;
    __shared__ __align__(16) USH lA[BM][32];
    __shared__ __align__(16) USH lB[128][32];
    int tid = threadIdx.x;
    int lane = tid & 63, wave = tid >> 6;
    int wr = wave >> 1, wc = wave & 1;
    int quad = lane >> 4, l15 = lane & 15;
    int m0 = blockIdx.x * BM, n0 = blockIdx.y * 128;

    int s_row = tid >> 2, s_k = (tid & 3) * 8;

    const USH* gA = A + (size_t)(m0 + s_row) * K + s_k;
    const USH* gB = WT + (size_t)(n0 + s_row) * K + s_k;
    USH* lA0 = &lA[0][0] + tid * 8;
    USH* lB0 = &lB[0][0] + tid * 8;

    floatx4 acc[MI][4] = {};

    for (int k0 = 0; k0 < K; k0 += 32) {
#pragma unroll
        for (int r = 0; r < BM / 64; r++)
            GLOAD16(gA + (size_t)r * 64 * K + k0, lA0 + r * 2048);
#pragma unroll
        for (int r = 0; r < 2; r++)
            GLOAD16(gB + (size_t)r * 64 * K + k0, lB0 + r * 2048);
        __syncthreads();

        bf16x8 bfr[4];
#pragma unroll
        for (int ni = 0; ni < 4; ni++)
            bfr[ni] = *(const bf16x8*)&lB[wc * 64 + ni * 16 + l15][quad * 8];
#pragma unroll
        for (int mi = 0; mi < MI; mi++) {
            bf16x8 afr = *(const bf16x8*)&lA[wr * (MI * 16) + mi * 16 + l15][quad * 8];
#pragma unroll
            for (int ni = 0; ni < 4; ni++)
                acc[mi][ni] = __builtin_amdgcn_mfma_f32_16x16x32_bf16(afr, bfr[ni], acc[mi][ni], 0, 0, 0);
        }
        __syncthreads();
    }

    float bias_v[4];
#pragma unroll
    for (int ni = 0; ni < 4; ni++) bias_v[ni] = bias[n0 + wc * 64 + ni * 16 + l15];

#pragma unroll
    for (int mi = 0; mi < MI; mi++) {
#pragma unroll
        for (int r = 0; r < 4; r++) {
            int row = m0 + wr * (MI * 16) + mi * 16 + quad * 4 + r;
            size_t base = (size_t)row * N;
#pragma unroll
            for (int ni = 0; ni < 4; ni++) {
                int col = n0 + wc * 64 + ni * 16 + l15;
                float v = acc[mi][ni][r] + bias_v[ni];
                if (EPI == 2) v = 0.5f * v * (1.f + erff(v * 0.70710678118f));
                if (EPI == 1 || EPI == 3) v += ldf(res + base + col);
                stf(out + base + col, v);
            }
        }
    }
}

// =====================================================================
// Flash distance-attention v5: bias folded into MFMA, Q-tile 128.
// sacc = mfma(zq_row, zk_row) = gv*d directly; p = exp(-max(sacc,0)).
// Block 256 (4 waves); wave owns 32 q-rows (2 16-row frags).
// grid = (B*H = 32, S/128 = 16).
// =====================================================================
__global__ __launch_bounds__(256) void attn5_kernel(const USH* __restrict__ zq_pack,
                                                    const USH* __restrict__ zk_pack,
                                                    const USH* __restrict__ value,
                                                    USH* __restrict__ attn_out) {
    int b = blockIdx.x >> 4, h = blockIdx.x & 15;
    int q0 = blockIdx.y * 128;
    int tid = threadIdx.x, lane = tid & 63, wq = tid >> 6;
    int quad = lane >> 4, l15 = lane & 15;

    __shared__ __align__(16) USH Qb[128][40];   // [q][k 0..32), extras baked
    __shared__ __align__(16) USH KbT[64][40];
    __shared__ __align__(16) USH VbT[64][72];   // [dh][key]
    __shared__ __align__(16) USH Pb[4][32][72]; // per-wave P [q][key]

    const size_t zrow0 = (size_t)b * 2048;
    const USH* zq = zq_pack + ((size_t)h * 4096 + zrow0) * 32;
    const USH* zk = zk_pack + ((size_t)h * 4096 + zrow0) * 32;
    const size_t vbase = zrow0 * 1024 + h * 64;

    {   // stage Q: 128 rows x 64 B (2 uint4 per thread)
        int row = tid >> 1, c0 = (tid & 1) * 16;
        const USH* src = zq + (size_t)(q0 + row) * 32 + c0;
        *(uint4*)&Qb[row][c0]     = *(const uint4*)src;
        *(uint4*)&Qb[row][c0 + 8] = *(const uint4*)(src + 8);
    }
    __syncthreads();

    bf16x8 afragQ[2];
    afragQ[0] = *(const bf16x8*)&Qb[wq * 32 + l15][quad * 8];
    afragQ[1] = *(const bf16x8*)&Qb[wq * 32 + 16 + l15][quad * 8];

    floatx4 oacc[2][4] = {};
    float lr[2][4] = {};

    for (int kt = 0; kt < 2048; kt += 64) {
        __syncthreads();
        {   // stage K: 64 rows x 64 B (1 uint4 per thread)
            int row = tid >> 2, c0 = (tid & 3) * 8;
            *(uint4*)&KbT[row][c0] = *(const uint4*)(zk + (size_t)(kt + row) * 32 + c0);
        }
        {   // stage V transposed: paired-key b32 writes (conflict-free)
            int key2 = (tid & 31) * 2;
            int dh0 = (tid >> 5) * 8;
            const USH* s0 = value + vbase + (size_t)(kt + key2) * 1024 + dh0;
            int4 ta = *(const int4*)s0;
            int4 tb = *(const int4*)(s0 + 1024);
            const USH* ua = (const USH*)&ta;
            const USH* ub = (const USH*)&tb;
#pragma unroll
            for (int e = 0; e < 8; e++) {
                unsigned int dw = (unsigned int)ua[e] | ((unsigned int)ub[e] << 16);
                *(unsigned int*)&VbT[dh0 + e][key2] = dw;
            }
        }
        __syncthreads();

        bf16x8 bk[4];
#pragma unroll
        for (int ni = 0; ni < 4; ni++)
            bk[ni] = *(const bf16x8*)&KbT[ni * 16 + l15][quad * 8];

#pragma unroll
        for (int qi = 0; qi < 2; qi++) {
            floatx4 sacc[4];
#pragma unroll
            for (int ni = 0; ni < 4; ni++) {
                floatx4 zz = {};
                sacc[ni] = __builtin_amdgcn_mfma_f32_16x16x32_bf16(afragQ[qi], bk[ni], zz, 0, 0, 0);
            }
#pragma unroll
            for (int r = 0; r < 4; r++) {
#pragma unroll
                for (int ni = 0; ni < 4; ni++) {
                    float t = fmaxf(sacc[ni][r], 0.f);
                    float pf = __expf(-t);
                    union { float f; unsigned int i; } cv; cv.f = pf;
                    Pb[wq][qi * 16 + quad * 4 + r][ni * 16 + l15] = (USH)(cv.i >> 16);
                    lr[qi][r] += pf;
                }
            }
        }

        // ---- PV (Pb wave-private; same-wave LDS in-order) ----
#pragma unroll
        for (int ks2 = 0; ks2 < 2; ks2++) {
            bf16x8 bv[4];
#pragma unroll
            for (int nd = 0; nd < 4; nd++)
                bv[nd] = *(const bf16x8*)&VbT[nd * 16 + l15][ks2 * 32 + quad * 8];
#pragma unroll
            for (int qi = 0; qi < 2; qi++) {
                bf16x8 ap = *(const bf16x8*)&Pb[wq][qi * 16 + l15][ks2 * 32 + quad * 8];
#pragma unroll
                for (int nd = 0; nd < 4; nd++)
                    oacc[qi][nd] = __builtin_amdgcn_mfma_f32_16x16x32_bf16(ap, bv[nd], oacc[qi][nd], 0, 0, 0);
            }
        }
    }

    // ---- epilogue ----
#pragma unroll
    for (int qi = 0; qi < 2; qi++) {
#pragma unroll
        for (int r = 0; r < 4; r++) {
            float s = lr[qi][r];
            s += __shfl_xor(s, 1); s += __shfl_xor(s, 2);
            s += __shfl_xor(s, 4); s += __shfl_xor(s, 8);
            float inv = 1.f / s;
            int row = q0 + wq * 32 + qi * 16 + quad * 4 + r;
            USH* o = attn_out + (zrow0 + row) * 1024 + h * 64;
#pragma unroll
            for (int nd = 0; nd < 4; nd++) o[nd * 16 + l15] = f2b(oacc[qi][nd][r] * inv);
        }
    }
}

// =====================================================================
// z_out = LN(z + z_next) over rows of 64. block = 64 (one wave) per row.
// =====================================================================
__global__ __launch_bounds__(64) void lnc_kernel(const float* __restrict__ z,
                                                 const float* __restrict__ zn,
                                                 const float* __restrict__ g,
                                                 const float* __restrict__ bb,
                                                 float* __restrict__ out) {
    int row = blockIdx.x, t = threadIdx.x;
    float v = z[(size_t)row * 64 + t] + zn[(size_t)row * 64 + t];
    float s = v, ss = v * v;
#pragma unroll
    for (int o = 32; o; o >>= 1) { s += __shfl_xor(s, o); ss += __shfl_xor(ss, o); }
    float mean = s * (1.f / 64.f);
    float rstd = rsqrtf(ss * (1.f / 64.f) - mean * mean + 1e-5f);
    out[(size_t)row * 64 + t] = (v - mean) * rstd * g[t] + bb[t];
}

// =====================================================================
extern "C" void kernel_launch(void* const* d_in, const int* in_sizes, int n_in,
                              void* d_out, int out_size, void* d_ws, size_t ws_size,
                              hipStream_t stream) {
    // workspace layout (61 MB):
    //   [0,8M)    value (bf16)      -- dead after attn
    //   [8,16M)   attn_o (bf16)     -- dead after wo-gemm
    //   [16,20M)  zq_pack (bf16 [16][4096][32]) -- dead after attn
    //   [20,24M)  zk_pack (bf16 [16][4096][32]) -- dead after attn
    //   [24,32M)  hn (bf16)         -- dead after znext
    //   [0,32M)   mid (bf16)        -- overlays the above (written step 8)
    //   [32,40M)  hn2 (bf16)
    //   [40,41M)  znext (f32)
    //   [41,43M)  wvT  [43,45M) woT  [45,53M) w1T  [53,61M) w2T
    // h1 (f32) lives in d_out's h region.
    char* p = (char*)d_ws;
    USH*   value   = (USH*)(p);
    USH*   attn_o  = (USH*)(p + ((size_t)8  << 20));
    USH*   zq_pack = (USH*)(p + ((size_t)16 << 20));
    USH*   zk_pack = (USH*)(p + ((size_t)20 << 20));
    USH*   hn      = (USH*)(p + ((size_t)24 << 20));
    USH*   mid     = (USH*)(p);
    USH*   hn2     = (USH*)(p + ((size_t)32 << 20));
    float* znext   = (float*)(p + ((size_t)40 << 20));
    USH*   wvT     = (USH*)(p + ((size_t)41 << 20));
    USH*   woT     = (USH*)(p + ((size_t)43 << 20));
    USH*   w1T     = (USH*)(p + ((size_t)45 << 20));
    USH*   w2T     = (USH*)(p + ((size_t)53 << 20));

    const float *h    = (const float*)d_in[0],  *z    = (const float*)d_in[1];
    const float *wv   = (const float*)d_in[2],  *bv   = (const float*)d_in[3];
    const float *wca  = (const float*)d_in[4],  *bca  = (const float*)d_in[5];
    const float *wcn  = (const float*)d_in[6],  *bcn  = (const float*)d_in[7];
    const float *wo   = (const float*)d_in[8],  *bo   = (const float*)d_in[9];
    const float *gam  = (const float*)d_in[10];
    const float *w1   = (const float*)d_in[11], *b1   = (const float*)d_in[12];
    const float *w2   = (const float*)d_in[13], *b2   = (const float*)d_in[14];
    const float *ln1g = (const float*)d_in[15], *ln1b = (const float*)d_in[16];
    const float *ln2g = (const float*)d_in[17], *ln2b = (const float*)d_in[18];
    const float *lncg = (const float*)d_in[19], *lncb = (const float*)d_in[20];

    float* out_h = (float*)d_out;
    float* out_z = out_h + (size_t)4096 * 1024;
    float* h1    = out_h;

    // 0. weight conversion (f32 [K][N] -> bf16 [N][K])
    transpose_f2b<<<dim3(16, 16), 256, 0, stream>>>(wv, wvT, 1024, 1024);
    transpose_f2b<<<dim3(16, 16), 256, 0, stream>>>(wo, woT, 1024, 1024);
    transpose_f2b<<<dim3(64, 16), 256, 0, stream>>>(w1, w1T, 1024, 4096);
    transpose_f2b<<<dim3(16, 64), 256, 0, stream>>>(w2, w2T, 4096, 1024);

    // 1. hn = LN1(h)
    ln_rows<float><<<4096, 256, 0, stream>>>(h, ln1g, ln1b, hn);
    // 2. packed attention operands from z
    zh_kernel<<<4096, 256, 0, stream>>>(z, wca, bca, gam, zq_pack, zk_pack);
    // 3. value = hn @ wv + bv
    gemm_kernel<0, 2, USH, USH><<<dim3(64, 8), 256, 0, stream>>>(hn, wvT, bv, (const USH*)nullptr, value, 4096, 1024, 1024);
    // 4. z_next = hn @ wcn + bcn
    znext_kernel<<<4096, 256, 0, stream>>>(hn, wcn, bcn, znext);
    // 5. attention (MFMA flash, bias-folded, Q-tile 128)
    attn5_kernel<<<dim3(32, 16), 256, 0, stream>>>(zq_pack, zk_pack, value, attn_o);
    // 6. h1 = h + attn_o @ wo + bo      (out f32 -> d_out h-region)
    gemm_kernel<1, 2, float, float><<<dim3(64, 8), 256, 0, stream>>>(attn_o, woT, bo, h, h1, 4096, 1024, 1024);
    // 7. hn2 = LN2(h1)
    ln_rows<float><<<4096, 256, 0, stream>>>(h1, ln2g, ln2b, hn2);
    // 8. mid = gelu(hn2 @ w1 + b1)
    gemm_kernel<2, 4, USH, USH><<<dim3(32, 32), 256, 0, stream>>>(hn2, w1T, b1, (const USH*)nullptr, mid, 4096, 4096, 1024);
    // 9. out_h = h1 + mid @ w2 + b2     (res==out same-thread, safe)
    gemm_kernel<3, 2, float, float><<<dim3(64, 8), 256, 0, stream>>>(mid, w2T, b2, h1, out_h, 4096, 1024, 4096);
    // 10. out_z = LN(z + znext)
    lnc_kernel<<<4096, 64, 0, stream>>>(z, znext, lncg, lncb, out_z);
}

// Round 9
// 448.426 us; speedup vs baseline: 3.4529x; 1.0541x over previous
//
#include <hip/hip_runtime.h>

#define USH unsigned short

// ---------- bf16 helpers (storage = unsigned short) ----------
__device__ __forceinline__ float b2f(USH u) {
    union { unsigned int i; float f; } x; x.i = ((unsigned int)u) << 16; return x.f;
}
__device__ __forceinline__ USH f2b(float f) {
    union { float f; unsigned int i; } x; x.f = f;
    unsigned int r = x.i + (0x7fffu + ((x.i >> 16) & 1u));  // RNE
    return (USH)(r >> 16);
}
__device__ __forceinline__ float ldf(const USH* p)  { return b2f(*p); }
__device__ __forceinline__ float ldf(const float* p){ return *p; }
__device__ __forceinline__ void stf(USH* p, float v)  { *p = f2b(v); }
__device__ __forceinline__ void stf(float* p, float v){ *p = v; }

// async global->LDS, 16B per lane (dest = wave-uniform base + lane*16)
#define GLOAD16(gp, lp) __builtin_amdgcn_global_load_lds(                     \
    (const __attribute__((address_space(1))) void*)(gp),                      \
    (__attribute__((address_space(3))) void*)(lp), 16, 0, 0)

typedef __attribute__((ext_vector_type(8))) __bf16 bf16x8;
typedef __attribute__((ext_vector_type(4))) float  floatx4;

// =====================================================================
// Weight transpose+convert: W[K][N] f32 -> WT[N][K] bf16.
// =====================================================================
__global__ __launch_bounds__(256) void transpose_f2b(const float* __restrict__ W,
                                                     USH* __restrict__ WT,
                                                     int K, int N) {
    __shared__ USH t[64][72];
    int n0 = blockIdx.x * 64, k0 = blockIdx.y * 64;
    int tid = threadIdx.x;
    int kr = tid >> 4, nc = (tid & 15) * 4;
#pragma unroll
    for (int r = 0; r < 4; r++) {
        int k = kr + r * 16;
        float4 v = *(const float4*)(W + (size_t)(k0 + k) * N + n0 + nc);
        t[nc + 0][k] = f2b(v.x); t[nc + 1][k] = f2b(v.y);
        t[nc + 2][k] = f2b(v.z); t[nc + 3][k] = f2b(v.w);
    }
    __syncthreads();
    int nr = tid >> 2, kc = (tid & 3) * 8;
#pragma unroll
    for (int r = 0; r < 2; r++) {
        int k = kc + r * 32;
        *(int4*)(WT + (size_t)(n0 + nr) * K + k0 + k) = *(const int4*)&t[nr][k];
    }
}

// =====================================================================
// LayerNorm rows of 1024. block=256, one block/row.
// =====================================================================
template <typename TX>
__global__ __launch_bounds__(256) void ln_rows(const TX* __restrict__ x,
                                               const float* __restrict__ g,
                                               const float* __restrict__ bb,
                                               USH* __restrict__ y) {
    int row = blockIdx.x, tid = threadIdx.x;
    const TX* xr = x + (size_t)row * 1024 + tid * 4;
    float v[4];
#pragma unroll
    for (int i = 0; i < 4; i++) v[i] = ldf(xr + i);
    float s  = v[0] + v[1] + v[2] + v[3];
    float ss = v[0]*v[0] + v[1]*v[1] + v[2]*v[2] + v[3]*v[3];
#pragma unroll
    for (int o = 32; o; o >>= 1) { s += __shfl_down(s, o); ss += __shfl_down(ss, o); }
    __shared__ float red[10];
    int w = tid >> 6;
    if ((tid & 63) == 0) { red[w] = s; red[4 + w] = ss; }
    __syncthreads();
    if (tid == 0) {
        float S = red[0] + red[1] + red[2] + red[3];
        float SS = red[4] + red[5] + red[6] + red[7];
        float mean = S * (1.f / 1024.f);
        float var  = SS * (1.f / 1024.f) - mean * mean;
        red[8] = mean; red[9] = rsqrtf(var + 1e-5f);
    }
    __syncthreads();
    float mean = red[8], rstd = red[9];
    USH* yr = y + (size_t)row * 1024 + tid * 4;
#pragma unroll
    for (int i = 0; i < 4; i++) {
        int c = tid * 4 + i;
        yr[i] = f2b((v[i] - mean) * rstd * g[c] + bb[c]);
    }
}

// =====================================================================
// zh = z @ wca + bca, emitting packed MFMA operand rows (head-major):
//  zq_pack[h][row][32]: [-2*gv*s (16)], [16]=gv*ks, [17]=gv, [18]=gv, 0..
//  zk_pack[h][row][32]: [ f2b(s) (16)], [16]=1.0,  [17]=ks_hi, [18]=ks_lo, 0..
// so that mfma(zq_row, zk_row) = gv * (qs + ks - 2 q.k) directly.
// =====================================================================
__global__ __launch_bounds__(256) void zh_kernel(const float* __restrict__ z,
                                                 const float* __restrict__ wca,
                                                 const float* __restrict__ bca,
                                                 const float* __restrict__ gamma,
                                                 USH* __restrict__ zq_pack,
                                                 USH* __restrict__ zk_pack) {
    int row = blockIdx.x, n = threadIdx.x;
    __shared__ float zrow[64];
    if (n < 64) zrow[n] = z[(size_t)row * 64 + n];
    __syncthreads();
    float s = bca[n];
#pragma unroll 8
    for (int k = 0; k < 64; k++) s = fmaf(zrow[k], wca[(size_t)k * 256 + n], s);
    int h = n >> 4, c = n & 15;
    float gv = log1pf(__expf(gamma[h]));   // softplus
    USH u = f2b(s);
    float sv = b2f(u);
    float sq = sv * sv;
    sq += __shfl_xor(sq, 1); sq += __shfl_xor(sq, 2);
    sq += __shfl_xor(sq, 4); sq += __shfl_xor(sq, 8);
    size_t base = ((size_t)h * 4096 + row) * 32;
    zk_pack[base + c] = u;
    zq_pack[base + c] = f2b(-2.f * gv * s);
    if (c == 0) {
        USH hi = f2b(sq);
        float lo = sq - b2f(hi);
        unsigned int kw0 = 0x3F80u | ((unsigned int)hi << 16);
        unsigned int kw1 = (unsigned int)f2b(lo);
        uint4 kv = {kw0, kw1, 0u, 0u};
        uint4 zz = {0u, 0u, 0u, 0u};
        *(uint4*)(zk_pack + base + 16) = kv;
        *(uint4*)(zk_pack + base + 24) = zz;
        unsigned int qw0 = (unsigned int)f2b(gv * sq) | ((unsigned int)f2b(gv) << 16);
        unsigned int qw1 = (unsigned int)f2b(gv);
        uint4 qv = {qw0, qw1, 0u, 0u};
        *(uint4*)(zq_pack + base + 16) = qv;
        *(uint4*)(zq_pack + base + 24) = zz;
    }
}

// =====================================================================
// z_next = hn(bf16 ws) @ wcn(f32) + bcn  (4096 rows, K=1024, N=64) -> f32
// =====================================================================
__global__ __launch_bounds__(256) void znext_kernel(const USH* __restrict__ hn,
                                                    const float* __restrict__ wcn,
                                                    const float* __restrict__ bcn,
                                                    float* __restrict__ zn) {
    int row = blockIdx.x, t = threadIdx.x;
    int n = t & 63, ks = t >> 6;
    const USH* a = hn + (size_t)row * 1024 + ks * 256;
    const float* w = wcn + (size_t)ks * 256 * 64 + n;
    float s = 0.f;
#pragma unroll 4
    for (int k = 0; k < 256; k++) s = fmaf(b2f(a[k]), w[(size_t)k * 64], s);
    __shared__ float part[4][64];
    part[ks][n] = s;
    __syncthreads();
    if (t < 64)
        zn[(size_t)row * 64 + t] = part[0][t] + part[1][t] + part[2][t] + part[3][t] + bcn[t];
}

// =====================================================================
// MFMA GEMM v3: BK=64, global_load_lds staging with XOR k-granule
// swizzle (8-elem granularity): physical slot k8 holds global granule
// k8 ^ (row&7); fragment reads XOR with (l15&7)*8 -> 2-way banks (free).
// Tile BM x 128 (BM = MI*32), 4 waves. XCD-affine grid (x = m-block).
// EPI: 0 = plain | 1 = +res | 2 = gelu | 3 = +res
// =====================================================================
template <int EPI, int MI, typename TRES, typename TOUT>
__global__ __launch_bounds__(256) void gemm_kernel(const USH* __restrict__ A,
                                                   const USH* __restrict__ WT,
                                                   const float* __restrict__ bias,
                                                   const TRES* __restrict__ res,
                                                   TOUT* __restrict__ out,
                                                   int M, int N, int K) {
    constexpr int BM = MI * 32;
    __shared__ __align__(16) USH lA[BM][64];
    __shared__ __align__(16) USH lB[128][64];
    int tid = threadIdx.x;
    int lane = tid & 63, wave = tid >> 6;
    int wr = wave >> 1, wc = wave & 1;
    int quad = lane >> 4, l15 = lane & 15;
    int m0 = blockIdx.x * BM, n0 = blockIdx.y * 128;

    int srow = tid >> 3;                 // 0..31 (rows per 4KB chunk)
    int k8   = tid & 7;                  // 16B granule within row
    int scol = (k8 ^ (srow & 7)) * 8;    // swizzled source column

    const USH* gA = A + (size_t)(m0 + srow) * K + scol;
    const USH* gB = WT + (size_t)(n0 + srow) * K + scol;
    USH* lA0 = &lA[0][0] + tid * 8;      // lane*16B dest
    USH* lB0 = &lB[0][0] + tid * 8;
    int xo = (l15 & 7) * 8;              // read-side XOR

    floatx4 acc[MI][4] = {};

    for (int k0 = 0; k0 < K; k0 += 64) {
#pragma unroll
        for (int c = 0; c < BM / 32; c++)
            GLOAD16(gA + (size_t)c * 32 * K + k0, lA0 + c * 2048);
#pragma unroll
        for (int c = 0; c < 4; c++)
            GLOAD16(gB + (size_t)c * 32 * K + k0, lB0 + c * 2048);
        __syncthreads();

#pragma unroll
        for (int ks = 0; ks < 2; ks++) {
            bf16x8 bfr[4];
#pragma unroll
            for (int ni = 0; ni < 4; ni++)
                bfr[ni] = *(const bf16x8*)&lB[wc * 64 + ni * 16 + l15][(ks * 32 + quad * 8) ^ xo];
#pragma unroll
            for (int mi = 0; mi < MI; mi++) {
                bf16x8 afr = *(const bf16x8*)&lA[wr * (MI * 16) + mi * 16 + l15][(ks * 32 + quad * 8) ^ xo];
#pragma unroll
                for (int ni = 0; ni < 4; ni++)
                    acc[mi][ni] = __builtin_amdgcn_mfma_f32_16x16x32_bf16(afr, bfr[ni], acc[mi][ni], 0, 0, 0);
            }
        }
        __syncthreads();
    }

    float bias_v[4];
#pragma unroll
    for (int ni = 0; ni < 4; ni++) bias_v[ni] = bias[n0 + wc * 64 + ni * 16 + l15];

#pragma unroll
    for (int mi = 0; mi < MI; mi++) {
#pragma unroll
        for (int r = 0; r < 4; r++) {
            int row = m0 + wr * (MI * 16) + mi * 16 + quad * 4 + r;
            size_t base = (size_t)row * N;
#pragma unroll
            for (int ni = 0; ni < 4; ni++) {
                int col = n0 + wc * 64 + ni * 16 + l15;
                float v = acc[mi][ni][r] + bias_v[ni];
                if (EPI == 2) v = 0.5f * v * (1.f + erff(v * 0.70710678118f));
                if (EPI == 1 || EPI == 3) v += ldf(res + base + col);
                stf(out + base + col, v);
            }
        }
    }
}

// =====================================================================
// Flash distance-attention v5 (R8-validated): bias folded into MFMA,
// Q-tile 128. grid = (B*H = 32, S/128 = 16), block 256.
// =====================================================================
__global__ __launch_bounds__(256) void attn5_kernel(const USH* __restrict__ zq_pack,
                                                    const USH* __restrict__ zk_pack,
                                                    const USH* __restrict__ value,
                                                    USH* __restrict__ attn_out) {
    int b = blockIdx.x >> 4, h = blockIdx.x & 15;
    int q0 = blockIdx.y * 128;
    int tid = threadIdx.x, lane = tid & 63, wq = tid >> 6;
    int quad = lane >> 4, l15 = lane & 15;

    __shared__ __align__(16) USH Qb[128][40];
    __shared__ __align__(16) USH KbT[64][40];
    __shared__ __align__(16) USH VbT[64][72];
    __shared__ __align__(16) USH Pb[4][32][72];

    const size_t zrow0 = (size_t)b * 2048;
    const USH* zq = zq_pack + ((size_t)h * 4096 + zrow0) * 32;
    const USH* zk = zk_pack + ((size_t)h * 4096 + zrow0) * 32;
    const size_t vbase = zrow0 * 1024 + h * 64;

    {
        int row = tid >> 1, c0 = (tid & 1) * 16;
        const USH* src = zq + (size_t)(q0 + row) * 32 + c0;
        *(uint4*)&Qb[row][c0]     = *(const uint4*)src;
        *(uint4*)&Qb[row][c0 + 8] = *(const uint4*)(src + 8);
    }
    __syncthreads();

    bf16x8 afragQ[2];
    afragQ[0] = *(const bf16x8*)&Qb[wq * 32 + l15][quad * 8];
    afragQ[1] = *(const bf16x8*)&Qb[wq * 32 + 16 + l15][quad * 8];

    floatx4 oacc[2][4] = {};
    float lr[2][4] = {};

    for (int kt = 0; kt < 2048; kt += 64) {
        __syncthreads();
        {
            int row = tid >> 2, c0 = (tid & 3) * 8;
            *(uint4*)&KbT[row][c0] = *(const uint4*)(zk + (size_t)(kt + row) * 32 + c0);
        }
        {
            int key2 = (tid & 31) * 2;
            int dh0 = (tid >> 5) * 8;
            const USH* s0 = value + vbase + (size_t)(kt + key2) * 1024 + dh0;
            int4 ta = *(const int4*)s0;
            int4 tb = *(const int4*)(s0 + 1024);
            const USH* ua = (const USH*)&ta;
            const USH* ub = (const USH*)&tb;
#pragma unroll
            for (int e = 0; e < 8; e++) {
                unsigned int dw = (unsigned int)ua[e] | ((unsigned int)ub[e] << 16);
                *(unsigned int*)&VbT[dh0 + e][key2] = dw;
            }
        }
        __syncthreads();

        bf16x8 bk[4];
#pragma unroll
        for (int ni = 0; ni < 4; ni++)
            bk[ni] = *(const bf16x8*)&KbT[ni * 16 + l15][quad * 8];

#pragma unroll
        for (int qi = 0; qi < 2; qi++) {
            floatx4 sacc[4];
#pragma unroll
            for (int ni = 0; ni < 4; ni++) {
                floatx4 zz = {};
                sacc[ni] = __builtin_amdgcn_mfma_f32_16x16x32_bf16(afragQ[qi], bk[ni], zz, 0, 0, 0);
            }
#pragma unroll
            for (int r = 0; r < 4; r++) {
#pragma unroll
                for (int ni = 0; ni < 4; ni++) {
                    float t = fmaxf(sacc[ni][r], 0.f);
                    float pf = __expf(-t);
                    union { float f; unsigned int i; } cv; cv.f = pf;
                    Pb[wq][qi * 16 + quad * 4 + r][ni * 16 + l15] = (USH)(cv.i >> 16);
                    lr[qi][r] += pf;
                }
            }
        }

#pragma unroll
        for (int ks2 = 0; ks2 < 2; ks2++) {
            bf16x8 bv[4];
#pragma unroll
            for (int nd = 0; nd < 4; nd++)
                bv[nd] = *(const bf16x8*)&VbT[nd * 16 + l15][ks2 * 32 + quad * 8];
#pragma unroll
            for (int qi = 0; qi < 2; qi++) {
                bf16x8 ap = *(const bf16x8*)&Pb[wq][qi * 16 + l15][ks2 * 32 + quad * 8];
#pragma unroll
                for (int nd = 0; nd < 4; nd++)
                    oacc[qi][nd] = __builtin_amdgcn_mfma_f32_16x16x32_bf16(ap, bv[nd], oacc[qi][nd], 0, 0, 0);
            }
        }
    }

#pragma unroll
    for (int qi = 0; qi < 2; qi++) {
#pragma unroll
        for (int r = 0; r < 4; r++) {
            float s = lr[qi][r];
            s += __shfl_xor(s, 1); s += __shfl_xor(s, 2);
            s += __shfl_xor(s, 4); s += __shfl_xor(s, 8);
            float inv = 1.f / s;
            int row = q0 + wq * 32 + qi * 16 + quad * 4 + r;
            USH* o = attn_out + (zrow0 + row) * 1024 + h * 64;
#pragma unroll
            for (int nd = 0; nd < 4; nd++) o[nd * 16 + l15] = f2b(oacc[qi][nd][r] * inv);
        }
    }
}

// =====================================================================
// z_out = LN(z + z_next) over rows of 64. block = 64 (one wave) per row.
// =====================================================================
__global__ __launch_bounds__(64) void lnc_kernel(const float* __restrict__ z,
                                                 const float* __restrict__ zn,
                                                 const float* __restrict__ g,
                                                 const float* __restrict__ bb,
                                                 float* __restrict__ out) {
    int row = blockIdx.x, t = threadIdx.x;
    float v = z[(size_t)row * 64 + t] + zn[(size_t)row * 64 + t];
    float s = v, ss = v * v;
#pragma unroll
    for (int o = 32; o; o >>= 1) { s += __shfl_xor(s, o); ss += __shfl_xor(ss, o); }
    float mean = s * (1.f / 64.f);
    float rstd = rsqrtf(ss * (1.f / 64.f) - mean * mean + 1e-5f);
    out[(size_t)row * 64 + t] = (v - mean) * rstd * g[t] + bb[t];
}

// =====================================================================
extern "C" void kernel_launch(void* const* d_in, const int* in_sizes, int n_in,
                              void* d_out, int out_size, void* d_ws, size_t ws_size,
                              hipStream_t stream) {
    // workspace layout (61 MB):
    //   [0,8M)    value    [8,16M) attn_o    [16,20M) zq_pack
    //   [20,24M)  zk_pack  [24,32M) hn
    //   [0,32M)   mid (overlays, written step 8)
    //   [32,40M)  hn2   [40,41M) znext
    //   [41,43M)  wvT  [43,45M) woT  [45,53M) w1T  [53,61M) w2T
    // h1 (f32) lives in d_out's h region.
    char* p = (char*)d_ws;
    USH*   value   = (USH*)(p);
    USH*   attn_o  = (USH*)(p + ((size_t)8  << 20));
    USH*   zq_pack = (USH*)(p + ((size_t)16 << 20));
    USH*   zk_pack = (USH*)(p + ((size_t)20 << 20));
    USH*   hn      = (USH*)(p + ((size_t)24 << 20));
    USH*   mid     = (USH*)(p);
    USH*   hn2     = (USH*)(p + ((size_t)32 << 20));
    float* znext   = (float*)(p + ((size_t)40 << 20));
    USH*   wvT     = (USH*)(p + ((size_t)41 << 20));
    USH*   woT     = (USH*)(p + ((size_t)43 << 20));
    USH*   w1T     = (USH*)(p + ((size_t)45 << 20));
    USH*   w2T     = (USH*)(p + ((size_t)53 << 20));

    const float *h    = (const float*)d_in[0],  *z    = (const float*)d_in[1];
    const float *wv   = (const float*)d_in[2],  *bv   = (const float*)d_in[3];
    const float *wca  = (const float*)d_in[4],  *bca  = (const float*)d_in[5];
    const float *wcn  = (const float*)d_in[6],  *bcn  = (const float*)d_in[7];
    const float *wo   = (const float*)d_in[8],  *bo   = (const float*)d_in[9];
    const float *gam  = (const float*)d_in[10];
    const float *w1   = (const float*)d_in[11], *b1   = (const float*)d_in[12];
    const float *w2   = (const float*)d_in[13], *b2   = (const float*)d_in[14];
    const float *ln1g = (const float*)d_in[15], *ln1b = (const float*)d_in[16];
    const float *ln2g = (const float*)d_in[17], *ln2b = (const float*)d_in[18];
    const float *lncg = (const float*)d_in[19], *lncb = (const float*)d_in[20];

    float* out_h = (float*)d_out;
    float* out_z = out_h + (size_t)4096 * 1024;
    float* h1    = out_h;

    // 0. weight conversion (f32 [K][N] -> bf16 [N][K])
    transpose_f2b<<<dim3(16, 16), 256, 0, stream>>>(wv, wvT, 1024, 1024);
    transpose_f2b<<<dim3(16, 16), 256, 0, stream>>>(wo, woT, 1024, 1024);
    transpose_f2b<<<dim3(64, 16), 256, 0, stream>>>(w1, w1T, 1024, 4096);
    transpose_f2b<<<dim3(16, 64), 256, 0, stream>>>(w2, w2T, 4096, 1024);

    // 1. hn = LN1(h)
    ln_rows<float><<<4096, 256, 0, stream>>>(h, ln1g, ln1b, hn);
    // 2. packed attention operands from z
    zh_kernel<<<4096, 256, 0, stream>>>(z, wca, bca, gam, zq_pack, zk_pack);
    // 3. value = hn @ wv + bv
    gemm_kernel<0, 2, USH, USH><<<dim3(64, 8), 256, 0, stream>>>(hn, wvT, bv, (const USH*)nullptr, value, 4096, 1024, 1024);
    // 4. z_next = hn @ wcn + bcn
    znext_kernel<<<4096, 256, 0, stream>>>(hn, wcn, bcn, znext);
    // 5. attention (MFMA flash, bias-folded, Q-tile 128)
    attn5_kernel<<<dim3(32, 16), 256, 0, stream>>>(zq_pack, zk_pack, value, attn_o);
    // 6. h1 = h + attn_o @ wo + bo      (out f32 -> d_out h-region)
    gemm_kernel<1, 2, float, float><<<dim3(64, 8), 256, 0, stream>>>(attn_o, woT, bo, h, h1, 4096, 1024, 1024);
    // 7. hn2 = LN2(h1)
    ln_rows<float><<<4096, 256, 0, stream>>>(h1, ln2g, ln2b, hn2);
    // 8. mid = gelu(hn2 @ w1 + b1)
    gemm_kernel<2, 4, USH, USH><<<dim3(32, 32), 256, 0, stream>>>(hn2, w1T, b1, (const USH*)nullptr, mid, 4096, 4096, 1024);
    // 9. out_h = h1 + mid @ w2 + b2     (res==out same-thread, safe)
    gemm_kernel<3, 2, float, float><<<dim3(64, 8), 256, 0, stream>>>(mid, w2T, b2, h1, out_h, 4096, 1024, 4096);
    // 10. out_z = LN(z + znext)
    lnc_kernel<<<4096, 64, 0, stream>>>(z, znext, lncg, lncb, out_z);
}

// Round 10
// 432.875 us; speedup vs baseline: 3.5770x; 1.0359x over previous
//
#include <hip/hip_runtime.h>

#define USH unsigned short

// ---------- bf16 helpers (storage = unsigned short) ----------
__device__ __forceinline__ float b2f(USH u) {
    union { unsigned int i; float f; } x; x.i = ((unsigned int)u) << 16; return x.f;
}
__device__ __forceinline__ USH f2b(float f) {
    union { float f; unsigned int i; } x; x.f = f;
    unsigned int r = x.i + (0x7fffu + ((x.i >> 16) & 1u));  // RNE
    return (USH)(r >> 16);
}
__device__ __forceinline__ float ldf(const USH* p)  { return b2f(*p); }
__device__ __forceinline__ float ldf(const float* p){ return *p; }
__device__ __forceinline__ void stf(USH* p, float v)  { *p = f2b(v); }
__device__ __forceinline__ void stf(float* p, float v){ *p = v; }

// async global->LDS, 16B per lane (dest = wave-uniform base + lane*16)
#define GLOAD16(gp, lp) __builtin_amdgcn_global_load_lds(                     \
    (const __attribute__((address_space(1))) void*)(gp),                      \
    (__attribute__((address_space(3))) void*)(lp), 16, 0, 0)

typedef __attribute__((ext_vector_type(8))) __bf16 bf16x8;
typedef __attribute__((ext_vector_type(4))) float  floatx4;

// =====================================================================
// Weight transpose+convert: W[K][N] f32 -> WT[N][K] bf16.
// =====================================================================
__global__ __launch_bounds__(256) void transpose_f2b(const float* __restrict__ W,
                                                     USH* __restrict__ WT,
                                                     int K, int N) {
    __shared__ USH t[64][72];
    int n0 = blockIdx.x * 64, k0 = blockIdx.y * 64;
    int tid = threadIdx.x;
    int kr = tid >> 4, nc = (tid & 15) * 4;
#pragma unroll
    for (int r = 0; r < 4; r++) {
        int k = kr + r * 16;
        float4 v = *(const float4*)(W + (size_t)(k0 + k) * N + n0 + nc);
        t[nc + 0][k] = f2b(v.x); t[nc + 1][k] = f2b(v.y);
        t[nc + 2][k] = f2b(v.z); t[nc + 3][k] = f2b(v.w);
    }
    __syncthreads();
    int nr = tid >> 2, kc = (tid & 3) * 8;
#pragma unroll
    for (int r = 0; r < 2; r++) {
        int k = kc + r * 32;
        *(int4*)(WT + (size_t)(n0 + nr) * K + k0 + k) = *(const int4*)&t[nr][k];
    }
}

// =====================================================================
// LayerNorm rows of 1024. block=256, one block/row.
// =====================================================================
template <typename TX>
__global__ __launch_bounds__(256) void ln_rows(const TX* __restrict__ x,
                                               const float* __restrict__ g,
                                               const float* __restrict__ bb,
                                               USH* __restrict__ y) {
    int row = blockIdx.x, tid = threadIdx.x;
    const TX* xr = x + (size_t)row * 1024 + tid * 4;
    float v[4];
#pragma unroll
    for (int i = 0; i < 4; i++) v[i] = ldf(xr + i);
    float s  = v[0] + v[1] + v[2] + v[3];
    float ss = v[0]*v[0] + v[1]*v[1] + v[2]*v[2] + v[3]*v[3];
#pragma unroll
    for (int o = 32; o; o >>= 1) { s += __shfl_down(s, o); ss += __shfl_down(ss, o); }
    __shared__ float red[10];
    int w = tid >> 6;
    if ((tid & 63) == 0) { red[w] = s; red[4 + w] = ss; }
    __syncthreads();
    if (tid == 0) {
        float S = red[0] + red[1] + red[2] + red[3];
        float SS = red[4] + red[5] + red[6] + red[7];
        float mean = S * (1.f / 1024.f);
        float var  = SS * (1.f / 1024.f) - mean * mean;
        red[8] = mean; red[9] = rsqrtf(var + 1e-5f);
    }
    __syncthreads();
    float mean = red[8], rstd = red[9];
    USH* yr = y + (size_t)row * 1024 + tid * 4;
#pragma unroll
    for (int i = 0; i < 4; i++) {
        int c = tid * 4 + i;
        yr[i] = f2b((v[i] - mean) * rstd * g[c] + bb[c]);
    }
}

// =====================================================================
// zh = z @ wca + bca, emitting packed MFMA operand rows (head-major),
// exp2-domain fold (gvl = softplus(gamma)*log2e):
//  zq_pack[h][row][32]: [ 2*gvl*s (16)], [16]=-gvl*ks, [17]=[18]=-gvl, 0..
//  zk_pack[h][row][32]: [ f2b(s) (16)],  [16]=1.0, [17]=ks_hi, [18]=ks_lo, 0..
// so mfma(zq_row, zk_row) = -gvl*(qs + ks - 2 q.k) <= 0 (log2 units),
// and p = exp2(sacc) is a single v_exp_f32.
// =====================================================================
__global__ __launch_bounds__(256) void zh_kernel(const float* __restrict__ z,
                                                 const float* __restrict__ wca,
                                                 const float* __restrict__ bca,
                                                 const float* __restrict__ gamma,
                                                 USH* __restrict__ zq_pack,
                                                 USH* __restrict__ zk_pack) {
    int row = blockIdx.x, n = threadIdx.x;
    __shared__ float zrow[64];
    if (n < 64) zrow[n] = z[(size_t)row * 64 + n];
    __syncthreads();
    float s = bca[n];
#pragma unroll 8
    for (int k = 0; k < 64; k++) s = fmaf(zrow[k], wca[(size_t)k * 256 + n], s);
    int h = n >> 4, c = n & 15;
    float gvl = log1pf(__expf(gamma[h])) * 1.44269504f;  // softplus * log2e
    USH u = f2b(s);
    float sv = b2f(u);
    float sq = sv * sv;
    sq += __shfl_xor(sq, 1); sq += __shfl_xor(sq, 2);
    sq += __shfl_xor(sq, 4); sq += __shfl_xor(sq, 8);
    size_t base = ((size_t)h * 4096 + row) * 32;
    zk_pack[base + c] = u;
    zq_pack[base + c] = f2b(2.f * gvl * s);
    if (c == 0) {
        USH hi = f2b(sq);
        float lo = sq - b2f(hi);
        unsigned int kw0 = 0x3F80u | ((unsigned int)hi << 16);
        unsigned int kw1 = (unsigned int)f2b(lo);
        uint4 kv = {kw0, kw1, 0u, 0u};
        uint4 zz = {0u, 0u, 0u, 0u};
        *(uint4*)(zk_pack + base + 16) = kv;
        *(uint4*)(zk_pack + base + 24) = zz;
        unsigned int qw0 = (unsigned int)f2b(-gvl * sq) | ((unsigned int)f2b(-gvl) << 16);
        unsigned int qw1 = (unsigned int)f2b(-gvl);
        uint4 qv = {qw0, qw1, 0u, 0u};
        *(uint4*)(zq_pack + base + 16) = qv;
        *(uint4*)(zq_pack + base + 24) = zz;
    }
}

// =====================================================================
// z_next = hn(bf16 ws) @ wcn(f32) + bcn  (4096 rows, K=1024, N=64) -> f32
// =====================================================================
__global__ __launch_bounds__(256) void znext_kernel(const USH* __restrict__ hn,
                                                    const float* __restrict__ wcn,
                                                    const float* __restrict__ bcn,
                                                    float* __restrict__ zn) {
    int row = blockIdx.x, t = threadIdx.x;
    int n = t & 63, ks = t >> 6;
    const USH* a = hn + (size_t)row * 1024 + ks * 256;
    const float* w = wcn + (size_t)ks * 256 * 64 + n;
    float s = 0.f;
#pragma unroll 4
    for (int k = 0; k < 256; k++) s = fmaf(b2f(a[k]), w[(size_t)k * 64], s);
    __shared__ float part[4][64];
    part[ks][n] = s;
    __syncthreads();
    if (t < 64)
        zn[(size_t)row * 64 + t] = part[0][t] + part[1][t] + part[2][t] + part[3][t] + bcn[t];
}

// =====================================================================
// MFMA GEMM v4: BK=64, XOR-swizzled global_load_lds staging.
// Tile (MI*32) x (NI*32); 4 waves in 2x2; XCD-affine grid (x = m-block).
// MI=NI=2 -> 64x64 tile, 16KB LDS, 4 blocks/CU at 1024-block grids.
// EPI: 0 = plain | 1 = +res | 2 = gelu | 3 = +res
// =====================================================================
template <int EPI, int MI, int NI, typename TRES, typename TOUT>
__global__ __launch_bounds__(256) void gemm_kernel(const USH* __restrict__ A,
                                                   const USH* __restrict__ WT,
                                                   const float* __restrict__ bias,
                                                   const TRES* __restrict__ res,
                                                   TOUT* __restrict__ out,
                                                   int M, int N, int K) {
    constexpr int BM = MI * 32;
    constexpr int BN = NI * 32;
    __shared__ __align__(16) USH lA[BM][64];
    __shared__ __align__(16) USH lB[BN][64];
    int tid = threadIdx.x;
    int lane = tid & 63, wave = tid >> 6;
    int wr = wave >> 1, wc = wave & 1;
    int quad = lane >> 4, l15 = lane & 15;
    int m0 = blockIdx.x * BM, n0 = blockIdx.y * BN;

    int srow = tid >> 3;                 // 0..31 (rows per 4KB chunk)
    int k8   = tid & 7;                  // 16B granule within row
    int scol = (k8 ^ (srow & 7)) * 8;    // swizzled source column

    const USH* gA = A + (size_t)(m0 + srow) * K + scol;
    const USH* gB = WT + (size_t)(n0 + srow) * K + scol;
    USH* lA0 = &lA[0][0] + tid * 8;      // lane*16B dest
    USH* lB0 = &lB[0][0] + tid * 8;
    int xo = (l15 & 7) * 8;              // read-side XOR

    floatx4 acc[MI][NI] = {};

    for (int k0 = 0; k0 < K; k0 += 64) {
#pragma unroll
        for (int c = 0; c < MI; c++)
            GLOAD16(gA + (size_t)c * 32 * K + k0, lA0 + c * 2048);
#pragma unroll
        for (int c = 0; c < NI; c++)
            GLOAD16(gB + (size_t)c * 32 * K + k0, lB0 + c * 2048);
        __syncthreads();

#pragma unroll
        for (int ks = 0; ks < 2; ks++) {
            bf16x8 bfr[NI];
#pragma unroll
            for (int ni = 0; ni < NI; ni++)
                bfr[ni] = *(const bf16x8*)&lB[wc * (NI * 16) + ni * 16 + l15][(ks * 32 + quad * 8) ^ xo];
#pragma unroll
            for (int mi = 0; mi < MI; mi++) {
                bf16x8 afr = *(const bf16x8*)&lA[wr * (MI * 16) + mi * 16 + l15][(ks * 32 + quad * 8) ^ xo];
#pragma unroll
                for (int ni = 0; ni < NI; ni++)
                    acc[mi][ni] = __builtin_amdgcn_mfma_f32_16x16x32_bf16(afr, bfr[ni], acc[mi][ni], 0, 0, 0);
            }
        }
        __syncthreads();
    }

    float bias_v[NI];
#pragma unroll
    for (int ni = 0; ni < NI; ni++) bias_v[ni] = bias[n0 + wc * (NI * 16) + ni * 16 + l15];

#pragma unroll
    for (int mi = 0; mi < MI; mi++) {
#pragma unroll
        for (int r = 0; r < 4; r++) {
            int row = m0 + wr * (MI * 16) + mi * 16 + quad * 4 + r;
            size_t base = (size_t)row * N;
#pragma unroll
            for (int ni = 0; ni < NI; ni++) {
                int col = n0 + wc * (NI * 16) + ni * 16 + l15;
                float v = acc[mi][ni][r] + bias_v[ni];
                if (EPI == 2) v = 0.5f * v * (1.f + erff(v * 0.70710678118f));
                if (EPI == 1 || EPI == 3) v += ldf(res + base + col);
                stf(out + base + col, v);
            }
        }
    }
}

// =====================================================================
// Flash distance-attention v6: exp2-domain fold, MFMA rowsum.
// sacc = mfma(zq,zk) = -gvl*d (log2 units, <= 0); p = exp2(sacc);
// rowsum via mfma(P, ones) -> no scalar l adds, no epilogue shuffles.
// Block 256 (4 waves x 32 q-rows); grid = (B*H = 32, S/128 = 16).
// =====================================================================
__global__ __launch_bounds__(256) void attn6_kernel(const USH* __restrict__ zq_pack,
                                                    const USH* __restrict__ zk_pack,
                                                    const USH* __restrict__ value,
                                                    USH* __restrict__ attn_out) {
    int b = blockIdx.x >> 4, h = blockIdx.x & 15;
    int q0 = blockIdx.y * 128;
    int tid = threadIdx.x, lane = tid & 63, wq = tid >> 6;
    int quad = lane >> 4, l15 = lane & 15;

    __shared__ __align__(16) USH Qb[128][40];
    __shared__ __align__(16) USH KbT[64][40];
    __shared__ __align__(16) USH VbT[64][72];
    __shared__ __align__(16) USH Pb[4][32][72];

    const size_t zrow0 = (size_t)b * 2048;
    const USH* zq = zq_pack + ((size_t)h * 4096 + zrow0) * 32;
    const USH* zk = zk_pack + ((size_t)h * 4096 + zrow0) * 32;
    const size_t vbase = zrow0 * 1024 + h * 64;

    {
        int row = tid >> 1, c0 = (tid & 1) * 16;
        const USH* src = zq + (size_t)(q0 + row) * 32 + c0;
        *(uint4*)&Qb[row][c0]     = *(const uint4*)src;
        *(uint4*)&Qb[row][c0 + 8] = *(const uint4*)(src + 8);
    }
    __syncthreads();

    bf16x8 afragQ[2];
    afragQ[0] = *(const bf16x8*)&Qb[wq * 32 + l15][quad * 8];
    afragQ[1] = *(const bf16x8*)&Qb[wq * 32 + 16 + l15][quad * 8];

    // ones fragment (bf16 1.0 x8)
    union { unsigned int u[4]; bf16x8 v; } onesu;
#pragma unroll
    for (int i = 0; i < 4; i++) onesu.u[i] = 0x3F803F80u;
    bf16x8 ones = onesu.v;

    floatx4 oacc[2][4] = {};
    floatx4 lacc[2] = {};

    for (int kt = 0; kt < 2048; kt += 64) {
        __syncthreads();
        {
            int row = tid >> 2, c0 = (tid & 3) * 8;
            *(uint4*)&KbT[row][c0] = *(const uint4*)(zk + (size_t)(kt + row) * 32 + c0);
        }
        {
            int key2 = (tid & 31) * 2;
            int dh0 = (tid >> 5) * 8;
            const USH* s0 = value + vbase + (size_t)(kt + key2) * 1024 + dh0;
            int4 ta = *(const int4*)s0;
            int4 tb = *(const int4*)(s0 + 1024);
            const USH* ua = (const USH*)&ta;
            const USH* ub = (const USH*)&tb;
#pragma unroll
            for (int e = 0; e < 8; e++) {
                unsigned int dw = (unsigned int)ua[e] | ((unsigned int)ub[e] << 16);
                *(unsigned int*)&VbT[dh0 + e][key2] = dw;
            }
        }
        __syncthreads();

        bf16x8 bk[4];
#pragma unroll
        for (int ni = 0; ni < 4; ni++)
            bk[ni] = *(const bf16x8*)&KbT[ni * 16 + l15][quad * 8];

#pragma unroll
        for (int qi = 0; qi < 2; qi++) {
            floatx4 sacc[4];
#pragma unroll
            for (int ni = 0; ni < 4; ni++) {
                floatx4 zz = {};
                sacc[ni] = __builtin_amdgcn_mfma_f32_16x16x32_bf16(afragQ[qi], bk[ni], zz, 0, 0, 0);
            }
#pragma unroll
            for (int r = 0; r < 4; r++) {
#pragma unroll
                for (int ni = 0; ni < 4; ni++) {
                    float pf = exp2f(sacc[ni][r]);   // single v_exp_f32
                    union { float f; unsigned int i; } cv; cv.f = pf;
                    Pb[wq][qi * 16 + quad * 4 + r][ni * 16 + l15] = (USH)(cv.i >> 16);
                }
            }
        }

        // ---- PV + rowsum (Pb wave-private; same-wave LDS in-order) ----
#pragma unroll
        for (int ks2 = 0; ks2 < 2; ks2++) {
            bf16x8 bv[4];
#pragma unroll
            for (int nd = 0; nd < 4; nd++)
                bv[nd] = *(const bf16x8*)&VbT[nd * 16 + l15][ks2 * 32 + quad * 8];
#pragma unroll
            for (int qi = 0; qi < 2; qi++) {
                bf16x8 ap = *(const bf16x8*)&Pb[wq][qi * 16 + l15][ks2 * 32 + quad * 8];
#pragma unroll
                for (int nd = 0; nd < 4; nd++)
                    oacc[qi][nd] = __builtin_amdgcn_mfma_f32_16x16x32_bf16(ap, bv[nd], oacc[qi][nd], 0, 0, 0);
                lacc[qi] = __builtin_amdgcn_mfma_f32_16x16x32_bf16(ap, ones, lacc[qi], 0, 0, 0);
            }
        }
    }

    // ---- epilogue: lacc holds the rowsum in every column ----
#pragma unroll
    for (int qi = 0; qi < 2; qi++) {
#pragma unroll
        for (int r = 0; r < 4; r++) {
            float inv = 1.f / lacc[qi][r];
            int row = q0 + wq * 32 + qi * 16 + quad * 4 + r;
            USH* o = attn_out + (zrow0 + row) * 1024 + h * 64;
#pragma unroll
            for (int nd = 0; nd < 4; nd++) o[nd * 16 + l15] = f2b(oacc[qi][nd][r] * inv);
        }
    }
}

// =====================================================================
// z_out = LN(z + z_next) over rows of 64. block = 64 (one wave) per row.
// =====================================================================
__global__ __launch_bounds__(64) void lnc_kernel(const float* __restrict__ z,
                                                 const float* __restrict__ zn,
                                                 const float* __restrict__ g,
                                                 const float* __restrict__ bb,
                                                 float* __restrict__ out) {
    int row = blockIdx.x, t = threadIdx.x;
    float v = z[(size_t)row * 64 + t] + zn[(size_t)row * 64 + t];
    float s = v, ss = v * v;
#pragma unroll
    for (int o = 32; o; o >>= 1) { s += __shfl_xor(s, o); ss += __shfl_xor(ss, o); }
    float mean = s * (1.f / 64.f);
    float rstd = rsqrtf(ss * (1.f / 64.f) - mean * mean + 1e-5f);
    out[(size_t)row * 64 + t] = (v - mean) * rstd * g[t] + bb[t];
}

// =====================================================================
extern "C" void kernel_launch(void* const* d_in, const int* in_sizes, int n_in,
                              void* d_out, int out_size, void* d_ws, size_t ws_size,
                              hipStream_t stream) {
    // workspace layout (61 MB):
    //   [0,8M)    value    [8,16M) attn_o    [16,20M) zq_pack
    //   [20,24M)  zk_pack  [24,32M) hn
    //   [0,32M)   mid (overlays, written step 8)
    //   [32,40M)  hn2   [40,41M) znext
    //   [41,43M)  wvT  [43,45M) woT  [45,53M) w1T  [53,61M) w2T
    // h1 (f32) lives in d_out's h region.
    char* p = (char*)d_ws;
    USH*   value   = (USH*)(p);
    USH*   attn_o  = (USH*)(p + ((size_t)8  << 20));
    USH*   zq_pack = (USH*)(p + ((size_t)16 << 20));
    USH*   zk_pack = (USH*)(p + ((size_t)20 << 20));
    USH*   hn      = (USH*)(p + ((size_t)24 << 20));
    USH*   mid     = (USH*)(p);
    USH*   hn2     = (USH*)(p + ((size_t)32 << 20));
    float* znext   = (float*)(p + ((size_t)40 << 20));
    USH*   wvT     = (USH*)(p + ((size_t)41 << 20));
    USH*   woT     = (USH*)(p + ((size_t)43 << 20));
    USH*   w1T     = (USH*)(p + ((size_t)45 << 20));
    USH*   w2T     = (USH*)(p + ((size_t)53 << 20));

    const float *h    = (const float*)d_in[0],  *z    = (const float*)d_in[1];
    const float *wv   = (const float*)d_in[2],  *bv   = (const float*)d_in[3];
    const float *wca  = (const float*)d_in[4],  *bca  = (const float*)d_in[5];
    const float *wcn  = (const float*)d_in[6],  *bcn  = (const float*)d_in[7];
    const float *wo   = (const float*)d_in[8],  *bo   = (const float*)d_in[9];
    const float *gam  = (const float*)d_in[10];
    const float *w1   = (const float*)d_in[11], *b1   = (const float*)d_in[12];
    const float *w2   = (const float*)d_in[13], *b2   = (const float*)d_in[14];
    const float *ln1g = (const float*)d_in[15], *ln1b = (const float*)d_in[16];
    const float *ln2g = (const float*)d_in[17], *ln2b = (const float*)d_in[18];
    const float *lncg = (const float*)d_in[19], *lncb = (const float*)d_in[20];

    float* out_h = (float*)d_out;
    float* out_z = out_h + (size_t)4096 * 1024;
    float* h1    = out_h;

    // 0. weight conversion (f32 [K][N] -> bf16 [N][K])
    transpose_f2b<<<dim3(16, 16), 256, 0, stream>>>(wv, wvT, 1024, 1024);
    transpose_f2b<<<dim3(16, 16), 256, 0, stream>>>(wo, woT, 1024, 1024);
    transpose_f2b<<<dim3(64, 16), 256, 0, stream>>>(w1, w1T, 1024, 4096);
    transpose_f2b<<<dim3(16, 64), 256, 0, stream>>>(w2, w2T, 4096, 1024);

    // 1. hn = LN1(h)
    ln_rows<float><<<4096, 256, 0, stream>>>(h, ln1g, ln1b, hn);
    // 2. packed attention operands from z (exp2-domain)
    zh_kernel<<<4096, 256, 0, stream>>>(z, wca, bca, gam, zq_pack, zk_pack);
    // 3. value = hn @ wv + bv           (64x64 tiles, 1024 blocks)
    gemm_kernel<0, 2, 2, USH, USH><<<dim3(64, 16), 256, 0, stream>>>(hn, wvT, bv, (const USH*)nullptr, value, 4096, 1024, 1024);
    // 4. z_next = hn @ wcn + bcn
    znext_kernel<<<4096, 256, 0, stream>>>(hn, wcn, bcn, znext);
    // 5. attention (MFMA flash, exp2-fold, MFMA rowsum)
    attn6_kernel<<<dim3(32, 16), 256, 0, stream>>>(zq_pack, zk_pack, value, attn_o);
    // 6. h1 = h + attn_o @ wo + bo      (out f32 -> d_out h-region)
    gemm_kernel<1, 2, 2, float, float><<<dim3(64, 16), 256, 0, stream>>>(attn_o, woT, bo, h, h1, 4096, 1024, 1024);
    // 7. hn2 = LN2(h1)
    ln_rows<float><<<4096, 256, 0, stream>>>(h1, ln2g, ln2b, hn2);
    // 8. mid = gelu(hn2 @ w1 + b1)      (128x128 tiles, 1024 blocks)
    gemm_kernel<2, 4, 4, USH, USH><<<dim3(32, 32), 256, 0, stream>>>(hn2, w1T, b1, (const USH*)nullptr, mid, 4096, 4096, 1024);
    // 9. out_h = h1 + mid @ w2 + b2     (res==out same-thread, safe)
    gemm_kernel<3, 2, 2, float, float><<<dim3(64, 16), 256, 0, stream>>>(mid, w2T, b2, h1, out_h, 4096, 1024, 4096);
    // 10. out_z = LN(z + znext)
    lnc_kernel<<<4096, 64, 0, stream>>>(z, znext, lncg, lncb, out_z);
}